// Round 3
// baseline (7735.023 us; speedup 1.0000x reference)
//
#include <hip/hip_runtime.h>

typedef __bf16 bf16;
typedef __bf16 bf16x8 __attribute__((ext_vector_type(8)));
typedef __bf16 bf16x4 __attribute__((ext_vector_type(4)));
typedef float  f32x4  __attribute__((ext_vector_type(4)));

#define T_LEN 70
#define BATCH 64
#define HDIM  1024
#define GDIM  4096
#define VOCAB 32000
#define TBROW (T_LEN * BATCH)   // 4480

#define MFMA16(a, b, c) __builtin_amdgcn_mfma_f32_16x16x32_bf16((a), (b), (c), 0, 0, 0)

// ---------------------------------------------------------------------------
// fp32 -> bf16 hi/lo split
// ---------------------------------------------------------------------------
__global__ void split_kernel(const float* __restrict__ w, bf16* __restrict__ hi,
                             bf16* __restrict__ lo, int n4) {
    int stride = gridDim.x * blockDim.x;
    for (int i = blockIdx.x * blockDim.x + threadIdx.x; i < n4; i += stride) {
        float4 v = reinterpret_cast<const float4*>(w)[i];
        bf16 h0 = (bf16)v.x, h1 = (bf16)v.y, h2 = (bf16)v.z, h3 = (bf16)v.w;
        bf16x4 hv = {h0, h1, h2, h3};
        bf16x4 lv = {(bf16)(v.x - (float)h0), (bf16)(v.y - (float)h1),
                     (bf16)(v.z - (float)h2), (bf16)(v.w - (float)h3)};
        reinterpret_cast<bf16x4*>(hi)[i] = hv;
        reinterpret_cast<bf16x4*>(lo)[i] = lv;
    }
}

__global__ void conv_kernel(const float* __restrict__ w, bf16* __restrict__ hi, int n4) {
    int stride = gridDim.x * blockDim.x;
    for (int i = blockIdx.x * blockDim.x + threadIdx.x; i < n4; i += stride) {
        float4 v = reinterpret_cast<const float4*>(w)[i];
        bf16x4 hv = {(bf16)v.x, (bf16)v.y, (bf16)v.z, (bf16)v.w};
        reinterpret_cast<bf16x4*>(hi)[i] = hv;
    }
}

__global__ void embed_kernel(const int* __restrict__ x, const float* __restrict__ emb,
                             bf16* __restrict__ xh, bf16* __restrict__ xl) {
    int row = blockIdx.x;
    int tok = x[row];
    const float4* src = reinterpret_cast<const float4*>(emb + (size_t)tok * HDIM);
    bf16x4* dh = reinterpret_cast<bf16x4*>(xh + (size_t)row * HDIM);
    bf16x4* dl = reinterpret_cast<bf16x4*>(xl + (size_t)row * HDIM);
    for (int i = threadIdx.x; i < HDIM / 4; i += blockDim.x) {
        float4 v = src[i];
        bf16 h0 = (bf16)v.x, h1 = (bf16)v.y, h2 = (bf16)v.z, h3 = (bf16)v.w;
        dh[i] = (bf16x4){h0, h1, h2, h3};
        dl[i] = (bf16x4){(bf16)(v.x - (float)h0), (bf16)(v.y - (float)h1),
                         (bf16)(v.z - (float)h2), (bf16)(v.w - (float)h3)};
    }
}

__global__ void init_kernel(const float* __restrict__ h0, const float* __restrict__ c0,
                            bf16* __restrict__ hsb, float* __restrict__ cst) {
    int i = blockIdx.x * blockDim.x + threadIdx.x;
    int l = i >> 16, r = i & 65535;
    float v = h0[i];
    bf16 h = (bf16)v;
    hsb[(size_t)((l * 2 + 0) * 2 + 0) * 65536 + r] = h;
    hsb[(size_t)((l * 2 + 0) * 2 + 1) * 65536 + r] = (bf16)(v - (float)h);
    cst[i] = c0[i];
}

// ---------------------------------------------------------------------------
// GEMM C = sum_p A_p B_p^T + bias.  128x128 tile, XOR-swizzled LDS (T2 fix),
// n-chunk-per-XCD / m-fastest order (B panel stays L2-resident, reused by all
// concurrent blocks of the XCD while A streams).
// ---------------------------------------------------------------------------
__global__ __launch_bounds__(256) void gemm_bt(
    const bf16* __restrict__ a0, const bf16* __restrict__ a1, const bf16* __restrict__ a2,
    const bf16* __restrict__ b0, const bf16* __restrict__ b1, const bf16* __restrict__ b2,
    int npass, int K, const float* __restrict__ bias, float* __restrict__ C, int ldc) {
    __shared__ __align__(16) char As[128 * 128];
    __shared__ __align__(16) char Bs[128 * 128];
    const int tid = threadIdx.x;
    const int wid = tid >> 6, lane = tid & 63;
    const int l15 = lane & 15, l4 = lane >> 4;

    // bijective XCD spread (m204), then within-XCD m-fastest (n slow)
    const int nbx = gridDim.x, mt = gridDim.y, nwg = nbx * mt;
    const int flat = blockIdx.y * nbx + blockIdx.x;
    const int xcd = flat & 7, o8 = flat >> 3;
    const int q8 = nwg >> 3, r8 = nwg & 7;
    const int wg = (xcd < r8 ? xcd * (q8 + 1) : r8 * (q8 + 1) + (xcd - r8) * q8) + o8;
    const int m0 = (wg % mt) * 128, n0 = (wg / mt) * 128;

    const int wr = (wid >> 1) * 64, wc = (wid & 1) * 64;
    const int sr = tid >> 3;                 // staging row 0..31 (+rr)
    const int sce = (tid & 7) * 8;           // staging col (elems)
    const int swz_st = (sr & 7) << 4;
    const int scb = (sce * 2) ^ swz_st;      // swizzled byte col
    const int swz_rd = (l15 & 7) << 4;

    f32x4 acc[4][4];
#pragma unroll
    for (int i = 0; i < 4; ++i)
#pragma unroll
        for (int j = 0; j < 4; ++j) acc[i][j] = (f32x4){0.f, 0.f, 0.f, 0.f};

    for (int p = 0; p < npass; ++p) {
        const bf16* A = (p == 0) ? a0 : ((p == 1) ? a1 : a2);
        const bf16* B = (p == 0) ? b0 : ((p == 1) ? b1 : b2);
        for (int k0 = 0; k0 < K; k0 += 64) {
            __syncthreads();
#pragma unroll
            for (int rr = 0; rr < 128; rr += 32) {
                const int row = rr + sr;
                *reinterpret_cast<uint4*>(As + row * 128 + scb) =
                    *reinterpret_cast<const uint4*>(&A[(size_t)(m0 + row) * K + k0 + sce]);
                *reinterpret_cast<uint4*>(Bs + row * 128 + scb) =
                    *reinterpret_cast<const uint4*>(&B[(size_t)(n0 + row) * K + k0 + sce]);
            }
            __syncthreads();
#pragma unroll
            for (int ks = 0; ks < 2; ++ks) {
                const int cb = (ks * 64 + l4 * 16) ^ swz_rd;
                bf16x8 af[4], bfr[4];
#pragma unroll
                for (int mi = 0; mi < 4; ++mi)
                    af[mi] = *reinterpret_cast<const bf16x8*>(As + (wr + mi * 16 + l15) * 128 + cb);
#pragma unroll
                for (int ni = 0; ni < 4; ++ni)
                    bfr[ni] = *reinterpret_cast<const bf16x8*>(Bs + (wc + ni * 16 + l15) * 128 + cb);
#pragma unroll
                for (int mi = 0; mi < 4; ++mi)
#pragma unroll
                    for (int ni = 0; ni < 4; ++ni)
                        acc[mi][ni] = MFMA16(af[mi], bfr[ni], acc[mi][ni]);
            }
        }
    }
#pragma unroll
    for (int ni = 0; ni < 4; ++ni) {
        const int col = n0 + wc + ni * 16 + l15;
        const float bv = bias[col];
#pragma unroll
        for (int mi = 0; mi < 4; ++mi) {
            const int row0 = m0 + wr + mi * 16 + l4 * 4;
#pragma unroll
            for (int r = 0; r < 4; ++r)
                C[(size_t)(row0 + r) * ldc + col] = acc[mi][ni][r] + bv;
        }
    }
}

// ---------------------------------------------------------------------------
// Persistent LSTM recurrence: 256 blocks x 512 thr, one launch for all
// 70 steps x 3 layers. Grid barriers (release/acquire, per-phase counters)
// only before layer1 and layer2 (l2->l0 transition touches disjoint buffers).
// Block = 64 batch rows x 4 h-cols (16 gate-cols); waves = 4 M-tiles x 2
// K-halves; A(hi+lo) and B(hi+lo) double-buffered, XOR-swizzled in LDS.
// c-state in registers.
// ---------------------------------------------------------------------------
__global__ __launch_bounds__(512, 1) void lstm_persist(
    const float* __restrict__ c0,
    const bf16* __restrict__ Wh0h, const bf16* __restrict__ Wh0l,
    const bf16* __restrict__ Wi1h, const bf16* __restrict__ Wi1l,
    const bf16* __restrict__ Wh1h, const bf16* __restrict__ Wh1l,
    const bf16* __restrict__ Wi2h, const bf16* __restrict__ Wi2l,
    const bf16* __restrict__ Wh2h, const bf16* __restrict__ Wh2l,
    const float* __restrict__ px0,
    const float* __restrict__ bh0, const float* __restrict__ bi1,
    const float* __restrict__ bh1, const float* __restrict__ bi2,
    const float* __restrict__ bh2,
    bf16* __restrict__ hsb, bf16* __restrict__ outh, int* __restrict__ bar) {
    // LDS: A-hi dbuf [0,32K) : buf*16384 ; A-lo dbuf [32K,64K) : 32768+buf*16384
    //      B dbuf [64K,80K) : 65536 + buf*8192 + hilo*4096
    //      pex aliases [0,4K)
    __shared__ __align__(16) char smem[81920];

    const int tid = threadIdx.x;
    const int wid = tid >> 6, lane = tid & 63;
    const int l15 = lane & 15, l4 = lane >> 4;
    const int wm = wid & 3, wn = wid >> 2;       // wn = K-half within chunk
    const int j0 = blockIdx.x * 4;               // 4 h-cols per block
    const int lq = l15 >> 2;                     // quarter 0..3
    const int lcol = lq * 1024 + j0 + (l15 & 3); // gate column (global)
    // A staging: thread -> (row sr, 16B piece ss)
    const int sr = tid >> 3, ss = tid & 7;
    const int swz_s = (sr & 7) << 4;
    const int awc0 = (ss * 16) ^ swz_s;
    const int awc1 = ((ss * 16) + 128) ^ swz_s;
    const int awrow = sr * 256;
    // B staging: thread -> (hilo, col-row, 16B piece)
    const int b_hl = tid >> 8;
    const int b_colr = (tid >> 4) & 15;
    const int b_kt = tid & 15;
    const int b_colg = (b_colr >> 2) * 1024 + j0 + (b_colr & 3);
    const int b_wbyte = (b_kt * 16) ^ ((b_colr & 7) << 4);
    // fragment reads
    const int a_frow = (wm * 16 + l15) * 256;
    const int b_frow = l15 * 256;
    const int swz_r = (l15 & 7) << 4;
    const int kbase = wn * 128;                  // this wave's k-half (bytes)
    // gate threads
    const int gb = tid >> 2, gj = tid & 3;

    float creg0 = 0.f, creg1 = 0.f, creg2 = 0.f;
    if (tid < 256) {
        creg0 = c0[0 * 65536 + gb * 1024 + j0 + gj];
        creg1 = c0[1 * 65536 + gb * 1024 + j0 + gj];
        creg2 = c0[2 * 65536 + gb * 1024 + j0 + gj];
    }

    auto hs = [&](int l, int pp, int hl) {
        return hsb + (((size_t)l * 2 + pp) * 2 + hl) * 65536;
    };

    int barid = 0;
    auto gbar = [&]() {
        __syncthreads();
        if (tid == 0) {
            __threadfence();
            __hip_atomic_fetch_add(&bar[barid], 1, __ATOMIC_ACQ_REL, __HIP_MEMORY_SCOPE_AGENT);
            while (__hip_atomic_load(&bar[barid], __ATOMIC_ACQUIRE, __HIP_MEMORY_SCOPE_AGENT)
                   < (int)gridDim.x)
                __builtin_amdgcn_s_sleep(2);
        }
        ++barid;
        __syncthreads();
    };

    auto run_cell = [&](const bf16* A0h, const bf16* A0l,
                        const bf16* B0h, const bf16* B0l,
                        const bf16* A1h, const bf16* A1l,
                        const bf16* B1h, const bf16* B1l,
                        int nch, const float* px, const float* bi,
                        const float* bh, float& cr,
                        bf16* h2h, bf16* h2l, bf16* oh) {
        f32x4 acc = (f32x4){0.f, 0.f, 0.f, 0.f};
        float pxv0 = 0.f, pxv1 = 0.f, pxv2 = 0.f, pxv3 = 0.f, biasv = 0.f;
        if (wn == 0) {
            biasv = bh[lcol] + (bi ? bi[lcol] : 0.f);
            if (px) {
                const int prow = wm * 16 + l4 * 4;
                pxv0 = px[(size_t)(prow + 0) * GDIM + lcol];
                pxv1 = px[(size_t)(prow + 1) * GDIM + lcol];
                pxv2 = px[(size_t)(prow + 2) * GDIM + lcol];
                pxv3 = px[(size_t)(prow + 3) * GDIM + lcol];
            }
        }

        auto loadA = [&](int cc, uint4& h0, uint4& h1, uint4& l0, uint4& l1) {
            const bf16* ph = (cc >= 8) ? A1h : A0h;
            const bf16* pl = (cc >= 8) ? A1l : A0l;
            const size_t e0 = (size_t)sr * HDIM + (cc & 7) * 128 + ss * 8;
            h0 = *reinterpret_cast<const uint4*>(ph + e0);
            h1 = *reinterpret_cast<const uint4*>(ph + e0 + 64);
            l0 = *reinterpret_cast<const uint4*>(pl + e0);
            l1 = *reinterpret_cast<const uint4*>(pl + e0 + 64);
        };
        auto loadB = [&](int cc, uint4& rb) {
            const bf16* pb = (cc >= 8) ? (b_hl ? B1l : B1h) : (b_hl ? B0l : B0h);
            rb = *reinterpret_cast<const uint4*>(
                pb + (size_t)b_colg * HDIM + (cc & 7) * 128 + b_kt * 8);
        };
        auto store = [&](int buf, const uint4& h0, const uint4& h1,
                         const uint4& l0, const uint4& l1, const uint4& rb) {
            char* ah = smem + buf * 16384 + awrow;
            char* al = smem + 32768 + buf * 16384 + awrow;
            *reinterpret_cast<uint4*>(ah + awc0) = h0;
            *reinterpret_cast<uint4*>(ah + awc1) = h1;
            *reinterpret_cast<uint4*>(al + awc0) = l0;
            *reinterpret_cast<uint4*>(al + awc1) = l1;
            *reinterpret_cast<uint4*>(smem + 65536 + buf * 8192 + b_hl * 4096 +
                                      b_colr * 256 + b_wbyte) = rb;
        };
        auto compute = [&](int buf) {
            const char* ah = smem + buf * 16384 + a_frow;
            const char* al = smem + 32768 + buf * 16384 + a_frow;
            const char* wh = smem + 65536 + buf * 8192 + b_frow;
            const char* wl = smem + 65536 + buf * 8192 + 4096 + b_frow;
#pragma unroll
            for (int ks = 0; ks < 2; ++ks) {
                const int cb = (kbase + ks * 64 + l4 * 16) ^ swz_r;
                bf16x8 a_h = *reinterpret_cast<const bf16x8*>(ah + cb);
                bf16x8 a_l = *reinterpret_cast<const bf16x8*>(al + cb);
                bf16x8 w_h = *reinterpret_cast<const bf16x8*>(wh + cb);
                bf16x8 w_l = *reinterpret_cast<const bf16x8*>(wl + cb);
                acc = MFMA16(a_h, w_h, acc);
                acc = MFMA16(a_h, w_l, acc);
                acc = MFMA16(a_l, w_h, acc);
            }
        };

        uint4 Ah0, Ah1, Al0, Al1, Bx;
        uint4 Ch0, Ch1, Cl0, Cl1, Dx;
        loadA(0, Ah0, Ah1, Al0, Al1);
        loadB(0, Bx);
        store(0, Ah0, Ah1, Al0, Al1, Bx);
        __syncthreads();
#pragma unroll 1
        for (int cc = 0; cc < nch; cc += 2) {
            loadA(cc + 1, Ch0, Ch1, Cl0, Cl1);
            loadB(cc + 1, Dx);
            compute(0);
            store(1, Ch0, Ch1, Cl0, Cl1, Dx);
            __syncthreads();
            const bool more = (cc + 2 < nch);
            if (more) {
                loadA(cc + 2, Ah0, Ah1, Al0, Al1);
                loadB(cc + 2, Bx);
            }
            compute(1);
            if (more) store(0, Ah0, Ah1, Al0, Al1, Bx);
            __syncthreads();
        }

        // epilogue: sum K-halves via LDS, gates, state update
        float* pex = reinterpret_cast<float*>(smem);   // [64][16]
        if (wn == 0) {
#pragma unroll
            for (int r = 0; r < 4; ++r) {
                const int row = wm * 16 + l4 * 4 + r;
                float v = acc[r] + biasv;
                if (px) v += (r == 0 ? pxv0 : r == 1 ? pxv1 : r == 2 ? pxv2 : pxv3);
                pex[row * 16 + l15] = v;
            }
        }
        __syncthreads();
        if (wn == 1) {
#pragma unroll
            for (int r = 0; r < 4; ++r)
                pex[(wm * 16 + l4 * 4 + r) * 16 + l15] += acc[r];
        }
        __syncthreads();
        if (tid < 256) {
            const float pi = pex[gb * 16 + 0 + gj];
            const float pf = pex[gb * 16 + 4 + gj];
            const float po = pex[gb * 16 + 8 + gj];
            const float pg = pex[gb * 16 + 12 + gj];
            const float ig = 1.f / (1.f + expf(-pi));
            const float fg = 1.f / (1.f + expf(-pf));
            const float og = 1.f / (1.f + expf(-po));
            const float gg = tanhf(pg);
            const float c2 = fg * cr + ig * gg;
            const float h2v = og * tanhf(c2);
            cr = c2;
            const int idx = gb * 1024 + j0 + gj;
            const bf16 hhi = (bf16)h2v;
            h2h[idx] = hhi;
            h2l[idx] = (bf16)(h2v - (float)hhi);
            if (oh) oh[idx] = hhi;
        }
        __syncthreads();   // protect smem before next phase's staging
    };

#pragma unroll 1
    for (int t = 0; t < T_LEN; ++t) {
        const int p = t & 1;
        // layer 0: A = h(0,t-1); px0 holds xe@Wi0^T + bi0
        run_cell(hs(0, p, 0), hs(0, p, 1), Wh0h, Wh0l,
                 hs(0, p, 0), hs(0, p, 1), Wh0h, Wh0l,
                 8, px0 + (size_t)t * BATCH * GDIM, nullptr, bh0, creg0,
                 hs(0, 1 - p, 0), hs(0, 1 - p, 1), nullptr);
        gbar();
        // layer 1: pair0 = (h(0,t), Wi1), pair1 = (h(1,t-1), Wh1)
        run_cell(hs(0, 1 - p, 0), hs(0, 1 - p, 1), Wi1h, Wi1l,
                 hs(1, p, 0), hs(1, p, 1), Wh1h, Wh1l,
                 16, nullptr, bi1, bh1, creg1,
                 hs(1, 1 - p, 0), hs(1, 1 - p, 1), nullptr);
        gbar();
        // layer 2: pair0 = (h(1,t), Wi2), pair1 = (h(2,t-1), Wh2)
        run_cell(hs(1, 1 - p, 0), hs(1, 1 - p, 1), Wi2h, Wi2l,
                 hs(2, p, 0), hs(2, p, 1), Wh2h, Wh2l,
                 16, nullptr, bi2, bh2, creg2,
                 hs(2, 1 - p, 0), hs(2, 1 - p, 1),
                 outh + (size_t)t * BATCH * HDIM);
    }
}

// ---------------------------------------------------------------------------
extern "C" void kernel_launch(void* const* d_in, const int* in_sizes, int n_in,
                              void* d_out, int out_size, void* d_ws, size_t ws_size,
                              hipStream_t stream) {
    (void)in_sizes; (void)n_in; (void)out_size; (void)ws_size;
    const int*   x   = (const int*)d_in[0];
    const float* h0  = (const float*)d_in[1];
    const float* c0  = (const float*)d_in[2];
    const float* emb = (const float*)d_in[3];
    const float* W[6] = { (const float*)d_in[4],  (const float*)d_in[6],
                          (const float*)d_in[8],  (const float*)d_in[10],
                          (const float*)d_in[12], (const float*)d_in[14] };
    const float* bi0 = (const float*)d_in[5];
    const float* bh0 = (const float*)d_in[7];
    const float* bi1 = (const float*)d_in[9];
    const float* bh1 = (const float*)d_in[11];
    const float* bi2 = (const float*)d_in[13];
    const float* bh2 = (const float*)d_in[15];
    const float* Wd  = (const float*)d_in[16];
    const float* bd  = (const float*)d_in[17];

    char* ws = (char*)d_ws;
    size_t off = 0;
    float* px0 = (float*)(ws + off); off += (size_t)TBROW * GDIM * 4;
    bf16* wsp[12];
    for (int i = 0; i < 12; ++i) { wsp[i] = (bf16*)(ws + off); off += (size_t)GDIM * HDIM * 2; }
    bf16* wdb  = (bf16*)(ws + off); off += (size_t)VOCAB * HDIM * 2;
    bf16* xeh  = (bf16*)(ws + off); off += (size_t)TBROW * HDIM * 2;
    bf16* xel  = (bf16*)(ws + off); off += (size_t)TBROW * HDIM * 2;
    bf16* outh = (bf16*)(ws + off); off += (size_t)TBROW * HDIM * 2;
    bf16* hsb  = (bf16*)(ws + off); off += (size_t)12 * BATCH * HDIM * 2;
    float* cst = (float*)(ws + off); off += (size_t)3 * BATCH * HDIM * 4;
    int*  bar  = (int*)(ws + off);  off += 1024;

    // weight hi/lo splits: wsp[0..1]=Wi0, [2..3]=Wh0, [4..5]=Wi1, [6..7]=Wh1,
    //                      [8..9]=Wi2, [10..11]=Wh2
    for (int i = 0; i < 6; ++i)
        split_kernel<<<1024, 256, 0, stream>>>(W[i], wsp[2 * i], wsp[2 * i + 1],
                                               GDIM * HDIM / 4);
    conv_kernel<<<2048, 256, 0, stream>>>(Wd, wdb, VOCAB * HDIM / 4);
    embed_kernel<<<TBROW, 256, 0, stream>>>(x, emb, xeh, xel);
    init_kernel<<<768, 256, 0, stream>>>(h0, c0, hsb, cst);
    hipMemsetAsync(bar, 0, 1024, stream);

    // px0 = xe @ Wi0^T + bi0 (split-3)
    dim3 gpx(GDIM / 128, TBROW / 128);
    gemm_bt<<<gpx, 256, 0, stream>>>(xeh, xel, xeh, wsp[0], wsp[0], wsp[1],
                                     3, HDIM, bi0, px0, GDIM);

    // whole recurrence in one persistent launch
    lstm_persist<<<256, 512, 0, stream>>>(
        c0,
        wsp[2], wsp[3],           // Wh0
        wsp[4], wsp[5],           // Wi1
        wsp[6], wsp[7],           // Wh1
        wsp[8], wsp[9],           // Wi2
        wsp[10], wsp[11],         // Wh2
        px0, bh0, bi1, bh1, bi2, bh2,
        hsb, outh, bar);

    // decoder: d_out = outh @ Wd^T + bd
    dim3 gdec(VOCAB / 128, TBROW / 128);
    gemm_bt<<<gdec, 256, 0, stream>>>(outh, nullptr, nullptr, wdb, nullptr, nullptr,
                                      1, HDIM, bd, (float*)d_out, VOCAB);
}

// Round 4
// 6534.245 us; speedup vs baseline: 1.1838x; 1.1838x over previous
//
#include <hip/hip_runtime.h>

typedef __bf16 bf16;
typedef __bf16 bf16x8 __attribute__((ext_vector_type(8)));
typedef __bf16 bf16x4 __attribute__((ext_vector_type(4)));
typedef float  f32x4  __attribute__((ext_vector_type(4)));

#define T_LEN 70
#define BATCH 64
#define HDIM  1024
#define GDIM  4096
#define VOCAB 32000
#define TBROW (T_LEN * BATCH)   // 4480

#define MFMA16(a, b, c) __builtin_amdgcn_mfma_f32_16x16x32_bf16((a), (b), (c), 0, 0, 0)

typedef const __attribute__((address_space(1))) void gas_void;
typedef __attribute__((address_space(3))) void las_void;

// ---------------------------------------------------------------------------
// fp32 -> bf16 hi/lo split
// ---------------------------------------------------------------------------
__global__ void split_kernel(const float* __restrict__ w, bf16* __restrict__ hi,
                             bf16* __restrict__ lo, int n4) {
    int stride = gridDim.x * blockDim.x;
    for (int i = blockIdx.x * blockDim.x + threadIdx.x; i < n4; i += stride) {
        float4 v = reinterpret_cast<const float4*>(w)[i];
        bf16 h0 = (bf16)v.x, h1 = (bf16)v.y, h2 = (bf16)v.z, h3 = (bf16)v.w;
        bf16x4 hv = {h0, h1, h2, h3};
        bf16x4 lv = {(bf16)(v.x - (float)h0), (bf16)(v.y - (float)h1),
                     (bf16)(v.z - (float)h2), (bf16)(v.w - (float)h3)};
        reinterpret_cast<bf16x4*>(hi)[i] = hv;
        reinterpret_cast<bf16x4*>(lo)[i] = lv;
    }
}

__global__ void conv_kernel(const float* __restrict__ w, bf16* __restrict__ hi, int n4) {
    int stride = gridDim.x * blockDim.x;
    for (int i = blockIdx.x * blockDim.x + threadIdx.x; i < n4; i += stride) {
        float4 v = reinterpret_cast<const float4*>(w)[i];
        bf16x4 hv = {(bf16)v.x, (bf16)v.y, (bf16)v.z, (bf16)v.w};
        reinterpret_cast<bf16x4*>(hi)[i] = hv;
    }
}

__global__ void embed_kernel(const int* __restrict__ x, const float* __restrict__ emb,
                             bf16* __restrict__ xh, bf16* __restrict__ xl) {
    int row = blockIdx.x;
    int tok = x[row];
    const float4* src = reinterpret_cast<const float4*>(emb + (size_t)tok * HDIM);
    bf16x4* dh = reinterpret_cast<bf16x4*>(xh + (size_t)row * HDIM);
    bf16x4* dl = reinterpret_cast<bf16x4*>(xl + (size_t)row * HDIM);
    for (int i = threadIdx.x; i < HDIM / 4; i += blockDim.x) {
        float4 v = src[i];
        bf16 h0 = (bf16)v.x, h1 = (bf16)v.y, h2 = (bf16)v.z, h3 = (bf16)v.w;
        dh[i] = (bf16x4){h0, h1, h2, h3};
        dl[i] = (bf16x4){(bf16)(v.x - (float)h0), (bf16)(v.y - (float)h1),
                         (bf16)(v.z - (float)h2), (bf16)(v.w - (float)h3)};
    }
}

// initial h stored at parity 1 (first reads occur at input-parity 1)
__global__ void init_kernel(const float* __restrict__ h0, const float* __restrict__ c0,
                            bf16* __restrict__ hsb, float* __restrict__ cst) {
    int i = blockIdx.x * blockDim.x + threadIdx.x;
    int l = i >> 16, r = i & 65535;
    float v = h0[i];
    bf16 h = (bf16)v;
    hsb[(size_t)((l * 2 + 1) * 2 + 0) * 65536 + r] = h;
    hsb[(size_t)((l * 2 + 1) * 2 + 1) * 65536 + r] = (bf16)(v - (float)h);
    cst[i] = c0[i];
}

// ---------------------------------------------------------------------------
// GEMM C = sum_p A_p B_p^T + bias. 128x128 tile, global_load_lds width-16
// staging with pre-swizzled global source (linear LDS dest), XOR-swizzled
// fragment reads. XCD-bijective remap, m-fastest within XCD.
// ---------------------------------------------------------------------------
__global__ __launch_bounds__(256) void gemm_bt(
    const bf16* __restrict__ a0, const bf16* __restrict__ a1, const bf16* __restrict__ a2,
    const bf16* __restrict__ b0, const bf16* __restrict__ b1, const bf16* __restrict__ b2,
    int npass, int K, const float* __restrict__ bias, float* __restrict__ C, int ldc) {
    __shared__ __align__(16) char As[128 * 128];
    __shared__ __align__(16) char Bs[128 * 128];
    const int tid = threadIdx.x;
    const int wid = tid >> 6, lane = tid & 63;
    const int l15 = lane & 15, l4 = lane >> 4;

    const int nbx = gridDim.x, mt = gridDim.y, nwg = nbx * mt;
    const int flat = blockIdx.y * nbx + blockIdx.x;
    const int xcd = flat & 7, o8 = flat >> 3;
    const int q8 = nwg >> 3, r8 = nwg & 7;
    const int wg = (xcd < r8 ? xcd * (q8 + 1) : r8 * (q8 + 1) + (xcd - r8) * q8) + o8;
    const int m0 = (wg % mt) * 128, n0 = (wg / mt) * 128;

    const int wr = (wid >> 1) * 64, wc = (wid & 1) * 64;
    const int swz_rd = (l15 & 15 & 7) << 4;
    // pre-swizzled global source for linear LDS dest (m173)
    const int rowL = lane >> 3;                       // 0..7 within chunk
    const int colE = (((lane & 7) ^ rowL)) << 3;      // element offset 0..56

    f32x4 acc[4][4];
#pragma unroll
    for (int i = 0; i < 4; ++i)
#pragma unroll
        for (int j = 0; j < 4; ++j) acc[i][j] = (f32x4){0.f, 0.f, 0.f, 0.f};

    for (int p = 0; p < npass; ++p) {
        const bf16* A = (p == 0) ? a0 : ((p == 1) ? a1 : a2);
        const bf16* B = (p == 0) ? b0 : ((p == 1) ? b1 : b2);
        for (int k0 = 0; k0 < K; k0 += 64) {
            __syncthreads();
#pragma unroll
            for (int c2 = 0; c2 < 4; ++c2) {
                const int ch = wid * 4 + c2;              // 16 chunks of 8 rows
                const int row = ch * 8 + rowL;
                __builtin_amdgcn_global_load_lds(
                    (gas_void*)(A + (size_t)(m0 + row) * K + k0 + colE),
                    (las_void*)(As + ch * 1024), 16, 0, 0);
                __builtin_amdgcn_global_load_lds(
                    (gas_void*)(B + (size_t)(n0 + row) * K + k0 + colE),
                    (las_void*)(Bs + ch * 1024), 16, 0, 0);
            }
            __syncthreads();
#pragma unroll
            for (int ks = 0; ks < 2; ++ks) {
                const int cb = (ks * 64 + l4 * 16) ^ swz_rd;
                bf16x8 af[4], bfr[4];
#pragma unroll
                for (int mi = 0; mi < 4; ++mi)
                    af[mi] = *reinterpret_cast<const bf16x8*>(As + (wr + mi * 16 + l15) * 128 + cb);
#pragma unroll
                for (int ni = 0; ni < 4; ++ni)
                    bfr[ni] = *reinterpret_cast<const bf16x8*>(Bs + (wc + ni * 16 + l15) * 128 + cb);
#pragma unroll
                for (int mi = 0; mi < 4; ++mi)
#pragma unroll
                    for (int ni = 0; ni < 4; ++ni)
                        acc[mi][ni] = MFMA16(af[mi], bfr[ni], acc[mi][ni]);
            }
        }
    }
#pragma unroll
    for (int ni = 0; ni < 4; ++ni) {
        const int col = n0 + wc + ni * 16 + l15;
        const float bv = bias[col];
#pragma unroll
        for (int mi = 0; mi < 4; ++mi) {
            const int row0 = m0 + wr + mi * 16 + l4 * 4;
#pragma unroll
            for (int r = 0; r < 4; ++r)
                C[(size_t)(row0 + r) * ldc + col] = acc[mi][ni][r] + bv;
        }
    }
}

// ---------------------------------------------------------------------------
// Wavefront-persistent LSTM: superstep s computes l0(s), l1(s-1), l2(s-2).
// 256 blocks x 512 thr; block owns 16 gate-cols (4 h-cols x 4 quarters) of
// ALL cells. 24 flat chunks/superstep (3 A-groups x 8), distance-2 prefetch,
// one grid barrier per superstep (71 total). c-state in registers.
// ---------------------------------------------------------------------------
struct ChunkRegs { uint4 a0, a1, a2, a3, b0, b1; };

__global__ __launch_bounds__(512, 1) void lstm_wave(
    const float* __restrict__ c0,
    const bf16* __restrict__ Wh0h, const bf16* __restrict__ Wh0l,
    const bf16* __restrict__ Wi1h, const bf16* __restrict__ Wi1l,
    const bf16* __restrict__ Wh1h, const bf16* __restrict__ Wh1l,
    const bf16* __restrict__ Wi2h, const bf16* __restrict__ Wi2l,
    const bf16* __restrict__ Wh2h, const bf16* __restrict__ Wh2l,
    const float* __restrict__ px0,
    const float* __restrict__ bh0, const float* __restrict__ bi1,
    const float* __restrict__ bh1, const float* __restrict__ bi2,
    const float* __restrict__ bh2,
    bf16* __restrict__ hsb, bf16* __restrict__ outh, int* __restrict__ bar) {
    // [0,65536): A dbuf  buf*32768 + {hi:0, lo:16384}
    // [65536,98304): B dbuf 65536 + buf*16384 + pass*8192 + {hi:0, lo:4096}
    // [98304,102400): pex float[64][16]
    __shared__ __align__(16) char smem[102400];

    const int tid = threadIdx.x;
    const int lane = tid & 63, wid = tid >> 6;
    const int l15 = lane & 15, l4 = lane >> 4;
    const int wm = wid & 3, wn = wid >> 2;
    const int j0 = blockIdx.x * 4;
    const int lq = l15 >> 2;
    const int lcol = lq * 1024 + j0 + (l15 & 3);
    // A staging
    const int sr = tid >> 3, ss = tid & 7;
    const int swz_s = (sr & 7) << 4;
    const int awc0 = (ss * 16) ^ swz_s;
    const int awc1 = (ss * 16 + 128) ^ swz_s;
    const int awrow = sr * 256;
    // B staging
    const int b_hl = tid >> 8;
    const int b_colr = (tid >> 4) & 15;
    const int b_kt = tid & 15;
    const int b_colg = (b_colr >> 2) * 1024 + j0 + (b_colr & 3);
    const int b_woff = b_hl * 4096 + b_colr * 256 + ((b_kt * 16) ^ ((b_colr & 7) << 4));
    // fragment reads
    const int a_frow = (wm * 16 + l15) * 256;
    const int b_frow = l15 * 256;
    const int swz_r = (l15 & 7) << 4;
    const int kb0 = wn * 128;
    // gates
    const int gb = tid >> 2, gj = tid & 3;

    float biasv0 = 0.f, biasv1 = 0.f, biasv2 = 0.f;
    if (wn == 0) {
        biasv0 = bh0[lcol];
        biasv1 = bi1[lcol] + bh1[lcol];
        biasv2 = bi2[lcol] + bh2[lcol];
    }
    float creg0 = 0.f, creg1 = 0.f, creg2 = 0.f;
    if (tid < 256) {
        creg0 = c0[0 * 65536 + gb * 1024 + j0 + gj];
        creg1 = c0[1 * 65536 + gb * 1024 + j0 + gj];
        creg2 = c0[2 * 65536 + gb * 1024 + j0 + gj];
    }

    auto hsp = [&](int l, int par, int hl) {
        return hsb + (((size_t)l * 2 + par) * 2 + hl) * 65536;
    };

    int barid = 0;
    auto gbar = [&]() {
        __syncthreads();
        if (tid == 0) {
            __threadfence();
            __hip_atomic_fetch_add(&bar[barid], 1, __ATOMIC_ACQ_REL, __HIP_MEMORY_SCOPE_AGENT);
            while (__hip_atomic_load(&bar[barid], __ATOMIC_ACQUIRE, __HIP_MEMORY_SCOPE_AGENT)
                   < (int)gridDim.x)
                __builtin_amdgcn_s_sleep(2);
        }
        ++barid;
        __syncthreads();
    };

#define PAH(c)  ((c) < 8 ? A0h : (c) < 16 ? A1h : A2h)
#define PAL(c)  ((c) < 8 ? A0l : (c) < 16 ? A1l : A2l)
#define PB0H(c) ((c) < 8 ? Wh0h : (c) < 16 ? Wh1h : Wh2h)
#define PB0L(c) ((c) < 8 ? Wh0l : (c) < 16 ? Wh1l : Wh2l)
#define PB1H(c) ((c) < 8 ? Wi1h : (c) < 16 ? Wi2h : Wh2h)
#define PB1L(c) ((c) < 8 ? Wi1l : (c) < 16 ? Wi2l : Wh2l)

#define ISSUE(c, R)                                                             \
    {                                                                           \
        const size_t e0 = (size_t)sr * HDIM + ((c) & 7) * 128 + ss * 8;         \
        R.a0 = *reinterpret_cast<const uint4*>(PAH(c) + e0);                    \
        R.a1 = *reinterpret_cast<const uint4*>(PAH(c) + e0 + 64);               \
        R.a2 = *reinterpret_cast<const uint4*>(PAL(c) + e0);                    \
        R.a3 = *reinterpret_cast<const uint4*>(PAL(c) + e0 + 64);               \
        const size_t eb = (size_t)b_colg * HDIM + ((c) & 7) * 128 + b_kt * 8;   \
        R.b0 = *reinterpret_cast<const uint4*>((b_hl ? PB0L(c) : PB0H(c)) + eb);\
        R.b1 = *reinterpret_cast<const uint4*>((b_hl ? PB1L(c) : PB1H(c)) + eb);\
    }

#define STOREC(buf, R)                                                          \
    {                                                                           \
        char* ab = smem + (buf) * 32768;                                        \
        *reinterpret_cast<uint4*>(ab + awrow + awc0) = R.a0;                    \
        *reinterpret_cast<uint4*>(ab + awrow + awc1) = R.a1;                    \
        *reinterpret_cast<uint4*>(ab + 16384 + awrow + awc0) = R.a2;            \
        *reinterpret_cast<uint4*>(ab + 16384 + awrow + awc1) = R.a3;            \
        char* bb = smem + 65536 + (buf) * 16384;                                \
        *reinterpret_cast<uint4*>(bb + b_woff) = R.b0;                          \
        *reinterpret_cast<uint4*>(bb + 8192 + b_woff) = R.b1;                   \
    }

#define COMPUTE(buf, ACCX, ACCY, TWO, AX, AY)                                   \
    {                                                                           \
        const char* ab = smem + (buf) * 32768;                                  \
        const char* bb = smem + 65536 + (buf) * 16384;                          \
        _Pragma("unroll") for (int ks = 0; ks < 2; ++ks) {                      \
            const int cb = (kb0 + ks * 64 + l4 * 16) ^ swz_r;                   \
            bf16x8 a_h = *reinterpret_cast<const bf16x8*>(ab + a_frow + cb);    \
            bf16x8 a_l = *reinterpret_cast<const bf16x8*>(ab + 16384 + a_frow + cb); \
            bf16x8 w0h = *reinterpret_cast<const bf16x8*>(bb + b_frow + cb);    \
            bf16x8 w0l = *reinterpret_cast<const bf16x8*>(bb + 4096 + b_frow + cb);  \
            if (AX) {                                                           \
                ACCX = MFMA16(a_h, w0h, ACCX);                                  \
                ACCX = MFMA16(a_h, w0l, ACCX);                                  \
                ACCX = MFMA16(a_l, w0h, ACCX);                                  \
            }                                                                   \
            if (TWO) {                                                          \
                bf16x8 w1h = *reinterpret_cast<const bf16x8*>(bb + 8192 + b_frow + cb);  \
                bf16x8 w1l = *reinterpret_cast<const bf16x8*>(bb + 12288 + b_frow + cb); \
                if (AY) {                                                       \
                    ACCY = MFMA16(a_h, w1h, ACCY);                              \
                    ACCY = MFMA16(a_h, w1l, ACCY);                              \
                    ACCY = MFMA16(a_l, w1h, ACCY);                              \
                }                                                               \
            }                                                                   \
        }                                                                       \
    }

#define EPILOGUE(ACC, BIASV, USEPX, ACT, HH, HL, OH, CREG)                      \
    {                                                                           \
        float* pex = reinterpret_cast<float*>(smem + 98304);                    \
        if ((ACT) && wn == 0) {                                                 \
            _Pragma("unroll") for (int r = 0; r < 4; ++r) {                     \
                const int row = wm * 16 + l4 * 4 + r;                           \
                float v = ACC[r] + BIASV;                                       \
                if (USEPX) v += pxv[r];                                         \
                pex[row * 16 + l15] = v;                                        \
            }                                                                   \
        }                                                                       \
        __syncthreads();                                                        \
        if ((ACT) && wn == 1) {                                                 \
            _Pragma("unroll") for (int r = 0; r < 4; ++r)                       \
                pex[(wm * 16 + l4 * 4 + r) * 16 + l15] += ACC[r];               \
        }                                                                       \
        __syncthreads();                                                        \
        if ((ACT) && tid < 256) {                                               \
            const float pi = pex[gb * 16 + 0 + gj];                             \
            const float pf = pex[gb * 16 + 4 + gj];                             \
            const float po = pex[gb * 16 + 8 + gj];                             \
            const float pg = pex[gb * 16 + 12 + gj];                            \
            const float ig = 1.f / (1.f + expf(-pi));                           \
            const float fg = 1.f / (1.f + expf(-pf));                           \
            const float og = 1.f / (1.f + expf(-po));                           \
            const float gg = tanhf(pg);                                         \
            const float c2v = fg * CREG + ig * gg;                              \
            const float h2v = og * tanhf(c2v);                                  \
            CREG = c2v;                                                         \
            const int idx = gb * 1024 + j0 + gj;                                \
            const bf16 hhi = (bf16)h2v;                                         \
            HH[idx] = hhi;                                                      \
            HL[idx] = (bf16)(h2v - (float)hhi);                                 \
            if (OH) ((bf16*)(OH))[idx] = hhi;                                   \
        }                                                                       \
    }

#pragma unroll 1
    for (int s = 0; s < T_LEN + 2; ++s) {
        const int ps = s & 1;
        const bool act0 = (s < T_LEN);
        const bool act1 = (s >= 1) && (s <= T_LEN);
        const bool act2 = (s >= 2);

        const bf16* A0h = hsp(0, 1 - ps, 0); const bf16* A0l = hsp(0, 1 - ps, 1);
        const bf16* A1h = hsp(1, ps, 0);     const bf16* A1l = hsp(1, ps, 1);
        const bf16* A2h = hsp(2, 1 - ps, 0); const bf16* A2l = hsp(2, 1 - ps, 1);
        bf16* wH0h = hsp(0, ps, 0);     bf16* wH0l = hsp(0, ps, 1);
        bf16* wH1h = hsp(1, 1 - ps, 0); bf16* wH1l = hsp(1, 1 - ps, 1);
        bf16* wH2h = hsp(2, ps, 0);     bf16* wH2l = hsp(2, ps, 1);
        bf16* ohp = act2 ? (outh + (size_t)(s - 2) * 65536) : nullptr;

        float pxv[4] = {0.f, 0.f, 0.f, 0.f};
        if (wn == 0 && act0) {
            const float* pxr = px0 + (size_t)s * BATCH * GDIM + (size_t)(wm * 16 + l4 * 4) * GDIM + lcol;
#pragma unroll
            for (int r = 0; r < 4; ++r) pxv[r] = pxr[(size_t)r * GDIM];
        }

        f32x4 acc0 = (f32x4){0.f, 0.f, 0.f, 0.f};
        f32x4 acc1 = (f32x4){0.f, 0.f, 0.f, 0.f};
        f32x4 acc2 = (f32x4){0.f, 0.f, 0.f, 0.f};

        ChunkRegs S0, S1;
        ISSUE(0, S0);
        ISSUE(1, S1);
        STOREC(0, S0);
        __syncthreads();

#pragma unroll
        for (int i = 0; i < 24; ++i) {
            if (i + 2 < 24) {
                if ((i & 1) == 0) ISSUE(i + 2, S0) else ISSUE(i + 2, S1)
            }
            if (i < 8)       COMPUTE(i & 1, acc0, acc1, 1, act0, act1)
            else if (i < 16) COMPUTE(i & 1, acc1, acc2, 1, act1, act2)
            else             COMPUTE(i & 1, acc2, acc2, 0, act2, act2)
            if (i + 1 < 24) {
                if ((i & 1) == 0) STOREC((i + 1) & 1, S1) else STOREC((i + 1) & 1, S0)
            }
            __syncthreads();
            if (i == 7)  EPILOGUE(acc0, biasv0, 1, act0, wH0h, wH0l, nullptr, creg0)
            if (i == 15) EPILOGUE(acc1, biasv1, 0, act1, wH1h, wH1l, nullptr, creg1)
            if (i == 23) EPILOGUE(acc2, biasv2, 0, act2, wH2h, wH2l, ohp, creg2)
        }

        if (s < T_LEN + 1) gbar();
    }
#undef PAH
#undef PAL
#undef PB0H
#undef PB0L
#undef PB1H
#undef PB1L
#undef ISSUE
#undef STOREC
#undef COMPUTE
#undef EPILOGUE
}

// ---------------------------------------------------------------------------
extern "C" void kernel_launch(void* const* d_in, const int* in_sizes, int n_in,
                              void* d_out, int out_size, void* d_ws, size_t ws_size,
                              hipStream_t stream) {
    (void)in_sizes; (void)n_in; (void)out_size; (void)ws_size;
    const int*   x   = (const int*)d_in[0];
    const float* h0  = (const float*)d_in[1];
    const float* c0  = (const float*)d_in[2];
    const float* emb = (const float*)d_in[3];
    const float* W[6] = { (const float*)d_in[4],  (const float*)d_in[6],
                          (const float*)d_in[8],  (const float*)d_in[10],
                          (const float*)d_in[12], (const float*)d_in[14] };
    const float* bi0 = (const float*)d_in[5];
    const float* bh0 = (const float*)d_in[7];
    const float* bi1 = (const float*)d_in[9];
    const float* bh1 = (const float*)d_in[11];
    const float* bi2 = (const float*)d_in[13];
    const float* bh2 = (const float*)d_in[15];
    const float* Wd  = (const float*)d_in[16];
    const float* bd  = (const float*)d_in[17];

    char* ws = (char*)d_ws;
    size_t off = 0;
    float* px0 = (float*)(ws + off); off += (size_t)TBROW * GDIM * 4;
    bf16* wsp[12];
    for (int i = 0; i < 12; ++i) { wsp[i] = (bf16*)(ws + off); off += (size_t)GDIM * HDIM * 2; }
    bf16* wdb  = (bf16*)(ws + off); off += (size_t)VOCAB * HDIM * 2;
    bf16* xeh  = (bf16*)(ws + off); off += (size_t)TBROW * HDIM * 2;
    bf16* xel  = (bf16*)(ws + off); off += (size_t)TBROW * HDIM * 2;
    bf16* outh = (bf16*)(ws + off); off += (size_t)TBROW * HDIM * 2;
    bf16* hsb  = (bf16*)(ws + off); off += (size_t)12 * BATCH * HDIM * 2;
    float* cst = (float*)(ws + off); off += (size_t)3 * BATCH * HDIM * 4;
    int*  bar  = (int*)(ws + off);  off += 1024;

    // wsp[0..1]=Wi0, [2..3]=Wh0, [4..5]=Wi1, [6..7]=Wh1, [8..9]=Wi2, [10..11]=Wh2
    for (int i = 0; i < 6; ++i)
        split_kernel<<<1024, 256, 0, stream>>>(W[i], wsp[2 * i], wsp[2 * i + 1],
                                               GDIM * HDIM / 4);
    conv_kernel<<<2048, 256, 0, stream>>>(Wd, wdb, VOCAB * HDIM / 4);
    embed_kernel<<<TBROW, 256, 0, stream>>>(x, emb, xeh, xel);
    init_kernel<<<768, 256, 0, stream>>>(h0, c0, hsb, cst);
    hipMemsetAsync(bar, 0, 1024, stream);

    // px0 = xe @ Wi0^T + bi0 (split-3)
    dim3 gpx(GDIM / 128, TBROW / 128);
    gemm_bt<<<gpx, 256, 0, stream>>>(xeh, xel, xeh, wsp[0], wsp[0], wsp[1],
                                     3, HDIM, bi0, px0, GDIM);

    // whole recurrence: wavefront-persistent
    lstm_wave<<<256, 512, 0, stream>>>(
        c0,
        wsp[2], wsp[3],           // Wh0
        wsp[4], wsp[5],           // Wi1
        wsp[6], wsp[7],           // Wh1
        wsp[8], wsp[9],           // Wi2
        wsp[10], wsp[11],         // Wh2
        px0, bh0, bi1, bh1, bi2, bh2,
        hsb, outh, bar);

    // decoder: d_out = outh @ Wd^T + bd
    dim3 gdec(VOCAB / 128, TBROW / 128);
    gemm_bt<<<gdec, 256, 0, stream>>>(outh, nullptr, nullptr, wdb, nullptr, nullptr,
                                      1, HDIM, bd, (float*)d_out, VOCAB);
}

// Round 5
// 5835.901 us; speedup vs baseline: 1.3254x; 1.1197x over previous
//
#include <hip/hip_runtime.h>

typedef __bf16 bf16;
typedef __bf16 bf16x8 __attribute__((ext_vector_type(8)));
typedef __bf16 bf16x4 __attribute__((ext_vector_type(4)));
typedef float  f32x4  __attribute__((ext_vector_type(4)));

#define T_LEN 70
#define BATCH 64
#define HDIM  1024
#define GDIM  4096
#define VOCAB 32000
#define TBROW (T_LEN * BATCH)   // 4480

#define MFMA16(a, b, c) __builtin_amdgcn_mfma_f32_16x16x32_bf16((a), (b), (c), 0, 0, 0)

typedef const __attribute__((address_space(1))) void gas_void;
typedef __attribute__((address_space(3))) void las_void;

// ---------------------------------------------------------------------------
// fp32 -> bf16 hi/lo split
// ---------------------------------------------------------------------------
__global__ void split_kernel(const float* __restrict__ w, bf16* __restrict__ hi,
                             bf16* __restrict__ lo, int n4) {
    int stride = gridDim.x * blockDim.x;
    for (int i = blockIdx.x * blockDim.x + threadIdx.x; i < n4; i += stride) {
        float4 v = reinterpret_cast<const float4*>(w)[i];
        bf16 h0 = (bf16)v.x, h1 = (bf16)v.y, h2 = (bf16)v.z, h3 = (bf16)v.w;
        bf16x4 hv = {h0, h1, h2, h3};
        bf16x4 lv = {(bf16)(v.x - (float)h0), (bf16)(v.y - (float)h1),
                     (bf16)(v.z - (float)h2), (bf16)(v.w - (float)h3)};
        reinterpret_cast<bf16x4*>(hi)[i] = hv;
        reinterpret_cast<bf16x4*>(lo)[i] = lv;
    }
}

__global__ void conv_kernel(const float* __restrict__ w, bf16* __restrict__ hi, int n4) {
    int stride = gridDim.x * blockDim.x;
    for (int i = blockIdx.x * blockDim.x + threadIdx.x; i < n4; i += stride) {
        float4 v = reinterpret_cast<const float4*>(w)[i];
        bf16x4 hv = {(bf16)v.x, (bf16)v.y, (bf16)v.z, (bf16)v.w};
        reinterpret_cast<bf16x4*>(hi)[i] = hv;
    }
}

__global__ void embed_kernel(const int* __restrict__ x, const float* __restrict__ emb,
                             bf16* __restrict__ xh, bf16* __restrict__ xl) {
    int row = blockIdx.x;
    int tok = x[row];
    const float4* src = reinterpret_cast<const float4*>(emb + (size_t)tok * HDIM);
    bf16x4* dh = reinterpret_cast<bf16x4*>(xh + (size_t)row * HDIM);
    bf16x4* dl = reinterpret_cast<bf16x4*>(xl + (size_t)row * HDIM);
    for (int i = threadIdx.x; i < HDIM / 4; i += blockDim.x) {
        float4 v = src[i];
        bf16 h0 = (bf16)v.x, h1 = (bf16)v.y, h2 = (bf16)v.z, h3 = (bf16)v.w;
        dh[i] = (bf16x4){h0, h1, h2, h3};
        dl[i] = (bf16x4){(bf16)(v.x - (float)h0), (bf16)(v.y - (float)h1),
                         (bf16)(v.z - (float)h2), (bf16)(v.w - (float)h3)};
    }
}

// initial h stored at parity 1 (first reads occur at input-parity 1)
__global__ void init_kernel(const float* __restrict__ h0, const float* __restrict__ c0,
                            bf16* __restrict__ hsb, float* __restrict__ cst) {
    int i = blockIdx.x * blockDim.x + threadIdx.x;
    int l = i >> 16, r = i & 65535;
    float v = h0[i];
    bf16 h = (bf16)v;
    hsb[(size_t)((l * 2 + 1) * 2 + 0) * 65536 + r] = h;
    hsb[(size_t)((l * 2 + 1) * 2 + 1) * 65536 + r] = (bf16)(v - (float)h);
    cst[i] = c0[i];
}

// ---------------------------------------------------------------------------
// GEMM C = sum_p A_p B_p^T + bias. 128x128 tile, global_load_lds width-16
// staging with pre-swizzled global source (linear LDS dest), XOR-swizzled
// fragment reads. XCD-bijective remap, m-fastest within XCD.
// ---------------------------------------------------------------------------
__global__ __launch_bounds__(256) void gemm_bt(
    const bf16* __restrict__ a0, const bf16* __restrict__ a1, const bf16* __restrict__ a2,
    const bf16* __restrict__ b0, const bf16* __restrict__ b1, const bf16* __restrict__ b2,
    int npass, int K, const float* __restrict__ bias, float* __restrict__ C, int ldc) {
    __shared__ __align__(16) char As[128 * 128];
    __shared__ __align__(16) char Bs[128 * 128];
    const int tid = threadIdx.x;
    const int wid = tid >> 6, lane = tid & 63;
    const int l15 = lane & 15, l4 = lane >> 4;

    const int nbx = gridDim.x, mt = gridDim.y, nwg = nbx * mt;
    const int flat = blockIdx.y * nbx + blockIdx.x;
    const int xcd = flat & 7, o8 = flat >> 3;
    const int q8 = nwg >> 3, r8 = nwg & 7;
    const int wg = (xcd < r8 ? xcd * (q8 + 1) : r8 * (q8 + 1) + (xcd - r8) * q8) + o8;
    const int m0 = (wg % mt) * 128, n0 = (wg / mt) * 128;

    const int wr = (wid >> 1) * 64, wc = (wid & 1) * 64;
    const int swz_rd = (l15 & 7) << 4;
    // pre-swizzled global source for linear LDS dest (m173)
    const int rowL = lane >> 3;                       // 0..7 within chunk
    const int colE = (((lane & 7) ^ rowL)) << 3;      // element offset 0..56

    f32x4 acc[4][4];
#pragma unroll
    for (int i = 0; i < 4; ++i)
#pragma unroll
        for (int j = 0; j < 4; ++j) acc[i][j] = (f32x4){0.f, 0.f, 0.f, 0.f};

    for (int p = 0; p < npass; ++p) {
        const bf16* A = (p == 0) ? a0 : ((p == 1) ? a1 : a2);
        const bf16* B = (p == 0) ? b0 : ((p == 1) ? b1 : b2);
        for (int k0 = 0; k0 < K; k0 += 64) {
            __syncthreads();
#pragma unroll
            for (int c2 = 0; c2 < 4; ++c2) {
                const int ch = wid * 4 + c2;              // 16 chunks of 8 rows
                const int row = ch * 8 + rowL;
                __builtin_amdgcn_global_load_lds(
                    (gas_void*)(A + (size_t)(m0 + row) * K + k0 + colE),
                    (las_void*)(As + ch * 1024), 16, 0, 0);
                __builtin_amdgcn_global_load_lds(
                    (gas_void*)(B + (size_t)(n0 + row) * K + k0 + colE),
                    (las_void*)(Bs + ch * 1024), 16, 0, 0);
            }
            __syncthreads();
#pragma unroll
            for (int ks = 0; ks < 2; ++ks) {
                const int cb = (ks * 64 + l4 * 16) ^ swz_rd;
                bf16x8 af[4], bfr[4];
#pragma unroll
                for (int mi = 0; mi < 4; ++mi)
                    af[mi] = *reinterpret_cast<const bf16x8*>(As + (wr + mi * 16 + l15) * 128 + cb);
#pragma unroll
                for (int ni = 0; ni < 4; ++ni)
                    bfr[ni] = *reinterpret_cast<const bf16x8*>(Bs + (wc + ni * 16 + l15) * 128 + cb);
#pragma unroll
                for (int mi = 0; mi < 4; ++mi)
#pragma unroll
                    for (int ni = 0; ni < 4; ++ni)
                        acc[mi][ni] = MFMA16(af[mi], bfr[ni], acc[mi][ni]);
            }
        }
    }
#pragma unroll
    for (int ni = 0; ni < 4; ++ni) {
        const int col = n0 + wc + ni * 16 + l15;
        const float bv = bias[col];
#pragma unroll
        for (int mi = 0; mi < 4; ++mi) {
            const int row0 = m0 + wr + mi * 16 + l4 * 4;
#pragma unroll
            for (int r = 0; r < 4; ++r)
                C[(size_t)(row0 + r) * ldc + col] = acc[mi][ni][r] + bv;
        }
    }
}

// ---------------------------------------------------------------------------
// Wavefront-persistent LSTM: superstep s computes l0(s), l1(s-1), l2(s-2).
// 256 blocks x 512 thr; block owns 16 gate-cols (4 h-cols x 4 quarters) of
// ALL cells. 24 flat chunks/superstep (3 A-groups x 8), distance-2 prefetch,
// one grid barrier per superstep. Barrier protocol: release-arrive,
// RELAXED spin (no per-poll cache invalidation!), single acquire fence.
// ---------------------------------------------------------------------------
struct ChunkRegs { uint4 a0, a1, a2, a3, b0, b1; };

__global__ __launch_bounds__(512, 1) void lstm_wave(
    const float* __restrict__ c0,
    const bf16* __restrict__ Wh0h, const bf16* __restrict__ Wh0l,
    const bf16* __restrict__ Wi1h, const bf16* __restrict__ Wi1l,
    const bf16* __restrict__ Wh1h, const bf16* __restrict__ Wh1l,
    const bf16* __restrict__ Wi2h, const bf16* __restrict__ Wi2l,
    const bf16* __restrict__ Wh2h, const bf16* __restrict__ Wh2l,
    const float* __restrict__ px0,
    const float* __restrict__ bh0, const float* __restrict__ bi1,
    const float* __restrict__ bh1, const float* __restrict__ bi2,
    const float* __restrict__ bh2,
    bf16* __restrict__ hsb, bf16* __restrict__ outh, int* __restrict__ bar) {
    // [0,65536): A dbuf  buf*32768 + {hi:0, lo:16384}
    // [65536,98304): B dbuf 65536 + buf*16384 + pass*8192 + {hi:0, lo:4096}
    // [98304,102400): pex float[64][16]
    __shared__ __align__(16) char smem[102400];

    const int tid = threadIdx.x;
    const int lane = tid & 63, wid = tid >> 6;
    const int l15 = lane & 15, l4 = lane >> 4;
    const int wm = wid & 3, wn = wid >> 2;
    const int j0 = blockIdx.x * 4;
    const int lq = l15 >> 2;
    const int lcol = lq * 1024 + j0 + (l15 & 3);
    // A staging
    const int sr = tid >> 3, ss = tid & 7;
    const int swz_s = (sr & 7) << 4;
    const int awc0 = (ss * 16) ^ swz_s;
    const int awc1 = (ss * 16 + 128) ^ swz_s;
    const int awrow = sr * 256;
    // B staging
    const int b_hl = tid >> 8;
    const int b_colr = (tid >> 4) & 15;
    const int b_kt = tid & 15;
    const int b_colg = (b_colr >> 2) * 1024 + j0 + (b_colr & 3);
    const int b_woff = b_hl * 4096 + b_colr * 256 + ((b_kt * 16) ^ ((b_colr & 7) << 4));
    // fragment reads
    const int a_frow = (wm * 16 + l15) * 256;
    const int b_frow = l15 * 256;
    const int swz_r = (l15 & 7) << 4;
    const int kb0 = wn * 128;
    // gates
    const int gb = tid >> 2, gj = tid & 3;

    float biasv0 = 0.f, biasv1 = 0.f, biasv2 = 0.f;
    if (wn == 0) {
        biasv0 = bh0[lcol];
        biasv1 = bi1[lcol] + bh1[lcol];
        biasv2 = bi2[lcol] + bh2[lcol];
    }
    float creg0 = 0.f, creg1 = 0.f, creg2 = 0.f;
    if (tid < 256) {
        creg0 = c0[0 * 65536 + gb * 1024 + j0 + gj];
        creg1 = c0[1 * 65536 + gb * 1024 + j0 + gj];
        creg2 = c0[2 * 65536 + gb * 1024 + j0 + gj];
    }

    auto hsp = [&](int l, int par, int hl) {
        return hsb + (((size_t)l * 2 + par) * 2 + hl) * 65536;
    };

    int barid = 0;
    auto gbar = [&]() {
        __syncthreads();
        if (tid == 0) {
            // arrive: release (one writeback), no invalidate
            __hip_atomic_fetch_add(&bar[barid], 1, __ATOMIC_RELEASE,
                                   __HIP_MEMORY_SCOPE_AGENT);
            // spin: RELAXED — reads coherence point, does NOT invalidate L1/L2
            while (__hip_atomic_load(&bar[barid], __ATOMIC_RELAXED,
                                     __HIP_MEMORY_SCOPE_AGENT) < (int)gridDim.x)
                __builtin_amdgcn_s_sleep(8);
            // single acquire per superstep: one invalidate, makes h visible
            __builtin_amdgcn_fence(__ATOMIC_ACQUIRE, "agent");
        }
        ++barid;
        __syncthreads();
    };

#define PAH(c)  ((c) < 8 ? A0h : (c) < 16 ? A1h : A2h)
#define PAL(c)  ((c) < 8 ? A0l : (c) < 16 ? A1l : A2l)
#define PB0H(c) ((c) < 8 ? Wh0h : (c) < 16 ? Wh1h : Wh2h)
#define PB0L(c) ((c) < 8 ? Wh0l : (c) < 16 ? Wh1l : Wh2l)
#define PB1H(c) ((c) < 8 ? Wi1h : (c) < 16 ? Wi2h : Wh2h)
#define PB1L(c) ((c) < 8 ? Wi1l : (c) < 16 ? Wi2l : Wh2l)

#define ISSUE(c, R)                                                             \
    {                                                                           \
        const size_t e0 = (size_t)sr * HDIM + ((c) & 7) * 128 + ss * 8;         \
        R.a0 = *reinterpret_cast<const uint4*>(PAH(c) + e0);                    \
        R.a1 = *reinterpret_cast<const uint4*>(PAH(c) + e0 + 64);               \
        R.a2 = *reinterpret_cast<const uint4*>(PAL(c) + e0);                    \
        R.a3 = *reinterpret_cast<const uint4*>(PAL(c) + e0 + 64);               \
        const size_t eb = (size_t)b_colg * HDIM + ((c) & 7) * 128 + b_kt * 8;   \
        R.b0 = *reinterpret_cast<const uint4*>((b_hl ? PB0L(c) : PB0H(c)) + eb);\
        R.b1 = *reinterpret_cast<const uint4*>((b_hl ? PB1L(c) : PB1H(c)) + eb);\
    }

#define STOREC(buf, R)                                                          \
    {                                                                           \
        char* ab = smem + (buf) * 32768;                                        \
        *reinterpret_cast<uint4*>(ab + awrow + awc0) = R.a0;                    \
        *reinterpret_cast<uint4*>(ab + awrow + awc1) = R.a1;                    \
        *reinterpret_cast<uint4*>(ab + 16384 + awrow + awc0) = R.a2;            \
        *reinterpret_cast<uint4*>(ab + 16384 + awrow + awc1) = R.a3;            \
        char* bb = smem + 65536 + (buf) * 16384;                                \
        *reinterpret_cast<uint4*>(bb + b_woff) = R.b0;                          \
        *reinterpret_cast<uint4*>(bb + 8192 + b_woff) = R.b1;                   \
    }

#define COMPUTE(buf, ACCX, ACCY, TWO, AX, AY)                                   \
    {                                                                           \
        const char* ab = smem + (buf) * 32768;                                  \
        const char* bb = smem + 65536 + (buf) * 16384;                          \
        _Pragma("unroll") for (int ks = 0; ks < 2; ++ks) {                      \
            const int cb = (kb0 + ks * 64 + l4 * 16) ^ swz_r;                   \
            bf16x8 a_h = *reinterpret_cast<const bf16x8*>(ab + a_frow + cb);    \
            bf16x8 a_l = *reinterpret_cast<const bf16x8*>(ab + 16384 + a_frow + cb); \
            bf16x8 w0h = *reinterpret_cast<const bf16x8*>(bb + b_frow + cb);    \
            bf16x8 w0l = *reinterpret_cast<const bf16x8*>(bb + 4096 + b_frow + cb);  \
            if (AX) {                                                           \
                ACCX = MFMA16(a_h, w0h, ACCX);                                  \
                ACCX = MFMA16(a_h, w0l, ACCX);                                  \
                ACCX = MFMA16(a_l, w0h, ACCX);                                  \
            }                                                                   \
            if (TWO) {                                                          \
                bf16x8 w1h = *reinterpret_cast<const bf16x8*>(bb + 8192 + b_frow + cb);  \
                bf16x8 w1l = *reinterpret_cast<const bf16x8*>(bb + 12288 + b_frow + cb); \
                if (AY) {                                                       \
                    ACCY = MFMA16(a_h, w1h, ACCY);                              \
                    ACCY = MFMA16(a_h, w1l, ACCY);                              \
                    ACCY = MFMA16(a_l, w1h, ACCY);                              \
                }                                                               \
            }                                                                   \
        }                                                                       \
    }

#define EPILOGUE(ACC, BIASV, USEPX, ACT, HH, HL, OH, CREG)                      \
    {                                                                           \
        float* pex = reinterpret_cast<float*>(smem + 98304);                    \
        if ((ACT) && wn == 0) {                                                 \
            _Pragma("unroll") for (int r = 0; r < 4; ++r) {                     \
                const int row = wm * 16 + l4 * 4 + r;                           \
                float v = ACC[r] + BIASV;                                       \
                if (USEPX) v += pxv[r];                                         \
                pex[row * 16 + l15] = v;                                        \
            }                                                                   \
        }                                                                       \
        __syncthreads();                                                        \
        if ((ACT) && wn == 1) {                                                 \
            _Pragma("unroll") for (int r = 0; r < 4; ++r)                       \
                pex[(wm * 16 + l4 * 4 + r) * 16 + l15] += ACC[r];               \
        }                                                                       \
        __syncthreads();                                                        \
        if ((ACT) && tid < 256) {                                               \
            const float pi = pex[gb * 16 + 0 + gj];                             \
            const float pf = pex[gb * 16 + 4 + gj];                             \
            const float po = pex[gb * 16 + 8 + gj];                             \
            const float pg = pex[gb * 16 + 12 + gj];                            \
            const float ig = 1.f / (1.f + expf(-pi));                           \
            const float fg = 1.f / (1.f + expf(-pf));                           \
            const float og = 1.f / (1.f + expf(-po));                           \
            const float gg = tanhf(pg);                                         \
            const float c2v = fg * CREG + ig * gg;                              \
            const float h2v = og * tanhf(c2v);                                  \
            CREG = c2v;                                                         \
            const int idx = gb * 1024 + j0 + gj;                                \
            const bf16 hhi = (bf16)h2v;                                         \
            HH[idx] = hhi;                                                      \
            HL[idx] = (bf16)(h2v - (float)hhi);                                 \
            if (OH) ((bf16*)(OH))[idx] = hhi;                                   \
        }                                                                       \
    }

#pragma unroll 1
    for (int s = 0; s < T_LEN + 2; ++s) {
        const int ps = s & 1;
        const bool act0 = (s < T_LEN);
        const bool act1 = (s >= 1) && (s <= T_LEN);
        const bool act2 = (s >= 2);

        const bf16* A0h = hsp(0, 1 - ps, 0); const bf16* A0l = hsp(0, 1 - ps, 1);
        const bf16* A1h = hsp(1, ps, 0);     const bf16* A1l = hsp(1, ps, 1);
        const bf16* A2h = hsp(2, 1 - ps, 0); const bf16* A2l = hsp(2, 1 - ps, 1);
        bf16* wH0h = hsp(0, ps, 0);     bf16* wH0l = hsp(0, ps, 1);
        bf16* wH1h = hsp(1, 1 - ps, 0); bf16* wH1l = hsp(1, 1 - ps, 1);
        bf16* wH2h = hsp(2, ps, 0);     bf16* wH2l = hsp(2, ps, 1);
        bf16* ohp = act2 ? (outh + (size_t)(s - 2) * 65536) : nullptr;

        float pxv[4] = {0.f, 0.f, 0.f, 0.f};
        if (wn == 0 && act0) {
            const float* pxr = px0 + (size_t)s * BATCH * GDIM + (size_t)(wm * 16 + l4 * 4) * GDIM + lcol;
#pragma unroll
            for (int r = 0; r < 4; ++r) pxv[r] = pxr[(size_t)r * GDIM];
        }

        f32x4 acc0 = (f32x4){0.f, 0.f, 0.f, 0.f};
        f32x4 acc1 = (f32x4){0.f, 0.f, 0.f, 0.f};
        f32x4 acc2 = (f32x4){0.f, 0.f, 0.f, 0.f};

        ChunkRegs S0, S1;
        ISSUE(0, S0);
        ISSUE(1, S1);
        STOREC(0, S0);
        __syncthreads();

#pragma unroll
        for (int i = 0; i < 24; ++i) {
            if (i + 2 < 24) {
                if ((i & 1) == 0) ISSUE(i + 2, S0) else ISSUE(i + 2, S1)
            }
            if (i < 8)       COMPUTE(i & 1, acc0, acc1, 1, act0, act1)
            else if (i < 16) COMPUTE(i & 1, acc1, acc2, 1, act1, act2)
            else             COMPUTE(i & 1, acc2, acc2, 0, act2, act2)
            if (i + 1 < 24) {
                if ((i & 1) == 0) STOREC((i + 1) & 1, S1) else STOREC((i + 1) & 1, S0)
            }
            __syncthreads();
            if (i == 7)  EPILOGUE(acc0, biasv0, 1, act0, wH0h, wH0l, nullptr, creg0)
            if (i == 15) EPILOGUE(acc1, biasv1, 0, act1, wH1h, wH1l, nullptr, creg1)
            if (i == 23) EPILOGUE(acc2, biasv2, 0, act2, wH2h, wH2l, ohp, creg2)
        }

        if (s < T_LEN + 1) gbar();
    }
#undef PAH
#undef PAL
#undef PB0H
#undef PB0L
#undef PB1H
#undef PB1L
#undef ISSUE
#undef STOREC
#undef COMPUTE
#undef EPILOGUE
}

// ---------------------------------------------------------------------------
extern "C" void kernel_launch(void* const* d_in, const int* in_sizes, int n_in,
                              void* d_out, int out_size, void* d_ws, size_t ws_size,
                              hipStream_t stream) {
    (void)in_sizes; (void)n_in; (void)out_size; (void)ws_size;
    const int*   x   = (const int*)d_in[0];
    const float* h0  = (const float*)d_in[1];
    const float* c0  = (const float*)d_in[2];
    const float* emb = (const float*)d_in[3];
    const float* W[6] = { (const float*)d_in[4],  (const float*)d_in[6],
                          (const float*)d_in[8],  (const float*)d_in[10],
                          (const float*)d_in[12], (const float*)d_in[14] };
    const float* bi0 = (const float*)d_in[5];
    const float* bh0 = (const float*)d_in[7];
    const float* bi1 = (const float*)d_in[9];
    const float* bh1 = (const float*)d_in[11];
    const float* bi2 = (const float*)d_in[13];
    const float* bh2 = (const float*)d_in[15];
    const float* Wd  = (const float*)d_in[16];
    const float* bd  = (const float*)d_in[17];

    char* ws = (char*)d_ws;
    size_t off = 0;
    float* px0 = (float*)(ws + off); off += (size_t)TBROW * GDIM * 4;
    bf16* wsp[12];
    for (int i = 0; i < 12; ++i) { wsp[i] = (bf16*)(ws + off); off += (size_t)GDIM * HDIM * 2; }
    bf16* wdb  = (bf16*)(ws + off); off += (size_t)VOCAB * HDIM * 2;
    bf16* xeh  = (bf16*)(ws + off); off += (size_t)TBROW * HDIM * 2;
    bf16* xel  = (bf16*)(ws + off); off += (size_t)TBROW * HDIM * 2;
    bf16* outh = (bf16*)(ws + off); off += (size_t)TBROW * HDIM * 2;
    bf16* hsb  = (bf16*)(ws + off); off += (size_t)12 * BATCH * HDIM * 2;
    float* cst = (float*)(ws + off); off += (size_t)3 * BATCH * HDIM * 4;
    int*  bar  = (int*)(ws + off);  off += 1024;

    // wsp[0..1]=Wi0, [2..3]=Wh0, [4..5]=Wi1, [6..7]=Wh1, [8..9]=Wi2, [10..11]=Wh2
    for (int i = 0; i < 6; ++i)
        split_kernel<<<1024, 256, 0, stream>>>(W[i], wsp[2 * i], wsp[2 * i + 1],
                                               GDIM * HDIM / 4);
    conv_kernel<<<2048, 256, 0, stream>>>(Wd, wdb, VOCAB * HDIM / 4);
    embed_kernel<<<TBROW, 256, 0, stream>>>(x, emb, xeh, xel);
    init_kernel<<<768, 256, 0, stream>>>(h0, c0, hsb, cst);
    hipMemsetAsync(bar, 0, 1024, stream);

    // px0 = xe @ Wi0^T + bi0 (split-3)
    dim3 gpx(GDIM / 128, TBROW / 128);
    gemm_bt<<<gpx, 256, 0, stream>>>(xeh, xel, xeh, wsp[0], wsp[0], wsp[1],
                                     3, HDIM, bi0, px0, GDIM);

    // whole recurrence: wavefront-persistent
    lstm_wave<<<256, 512, 0, stream>>>(
        c0,
        wsp[2], wsp[3],           // Wh0
        wsp[4], wsp[5],           // Wi1
        wsp[6], wsp[7],           // Wh1
        wsp[8], wsp[9],           // Wi2
        wsp[10], wsp[11],         // Wh2
        px0, bh0, bi1, bh1, bi2, bh2,
        hsb, outh, bar);

    // decoder: d_out = outh @ Wd^T + bd
    dim3 gdec(VOCAB / 128, TBROW / 128);
    gemm_bt<<<gdec, 256, 0, stream>>>(outh, nullptr, nullptr, wdb, nullptr, nullptr,
                                      1, HDIM, bd, (float*)d_out, VOCAB);
}

// Round 6
// 3036.224 us; speedup vs baseline: 2.5476x; 1.9221x over previous
//
#include <hip/hip_runtime.h>

typedef __bf16 bf16;
typedef __bf16 bf16x8 __attribute__((ext_vector_type(8)));
typedef __bf16 bf16x4 __attribute__((ext_vector_type(4)));
typedef float  f32x4  __attribute__((ext_vector_type(4)));

#define T_LEN 70
#define BATCH 64
#define HDIM  1024
#define GDIM  4096
#define VOCAB 32000
#define TBROW (T_LEN * BATCH)   // 4480

#define MFMA16(a, b, c) __builtin_amdgcn_mfma_f32_16x16x32_bf16((a), (b), (c), 0, 0, 0)

typedef const __attribute__((address_space(1))) void gas_void;
typedef __attribute__((address_space(3))) void las_void;

// ---------------------------------------------------------------------------
// fp32 -> bf16 hi/lo split
// ---------------------------------------------------------------------------
__global__ void split_kernel(const float* __restrict__ w, bf16* __restrict__ hi,
                             bf16* __restrict__ lo, int n4) {
    int stride = gridDim.x * blockDim.x;
    for (int i = blockIdx.x * blockDim.x + threadIdx.x; i < n4; i += stride) {
        float4 v = reinterpret_cast<const float4*>(w)[i];
        bf16 h0 = (bf16)v.x, h1 = (bf16)v.y, h2 = (bf16)v.z, h3 = (bf16)v.w;
        bf16x4 hv = {h0, h1, h2, h3};
        bf16x4 lv = {(bf16)(v.x - (float)h0), (bf16)(v.y - (float)h1),
                     (bf16)(v.z - (float)h2), (bf16)(v.w - (float)h3)};
        reinterpret_cast<bf16x4*>(hi)[i] = hv;
        reinterpret_cast<bf16x4*>(lo)[i] = lv;
    }
}

__global__ void conv_kernel(const float* __restrict__ w, bf16* __restrict__ hi, int n4) {
    int stride = gridDim.x * blockDim.x;
    for (int i = blockIdx.x * blockDim.x + threadIdx.x; i < n4; i += stride) {
        float4 v = reinterpret_cast<const float4*>(w)[i];
        bf16x4 hv = {(bf16)v.x, (bf16)v.y, (bf16)v.z, (bf16)v.w};
        reinterpret_cast<bf16x4*>(hi)[i] = hv;
    }
}

__global__ void embed_kernel(const int* __restrict__ x, const float* __restrict__ emb,
                             bf16* __restrict__ xh, bf16* __restrict__ xl) {
    int row = blockIdx.x;
    int tok = x[row];
    const float4* src = reinterpret_cast<const float4*>(emb + (size_t)tok * HDIM);
    bf16x4* dh = reinterpret_cast<bf16x4*>(xh + (size_t)row * HDIM);
    bf16x4* dl = reinterpret_cast<bf16x4*>(xl + (size_t)row * HDIM);
    for (int i = threadIdx.x; i < HDIM / 4; i += blockDim.x) {
        float4 v = src[i];
        bf16 h0 = (bf16)v.x, h1 = (bf16)v.y, h2 = (bf16)v.z, h3 = (bf16)v.w;
        dh[i] = (bf16x4){h0, h1, h2, h3};
        dl[i] = (bf16x4){(bf16)(v.x - (float)h0), (bf16)(v.y - (float)h1),
                         (bf16)(v.z - (float)h2), (bf16)(v.w - (float)h3)};
    }
}

// initial h stored at parity 1 (first reads occur at input-parity 1)
__global__ void init_kernel(const float* __restrict__ h0, const float* __restrict__ c0,
                            bf16* __restrict__ hsb, float* __restrict__ cst) {
    int i = blockIdx.x * blockDim.x + threadIdx.x;
    int l = i >> 16, r = i & 65535;
    float v = h0[i];
    bf16 h = (bf16)v;
    hsb[(size_t)((l * 2 + 1) * 2 + 0) * 65536 + r] = h;
    hsb[(size_t)((l * 2 + 1) * 2 + 1) * 65536 + r] = (bf16)(v - (float)h);
    cst[i] = c0[i];
}

// ---------------------------------------------------------------------------
// GEMM C = sum_p A_p B_p^T + bias. 128x128 tile, global_load_lds width-16
// staging with pre-swizzled global source (linear LDS dest), XOR-swizzled
// fragment reads. XCD-bijective remap, m-fastest within XCD.
// ---------------------------------------------------------------------------
__global__ __launch_bounds__(256) void gemm_bt(
    const bf16* __restrict__ a0, const bf16* __restrict__ a1, const bf16* __restrict__ a2,
    const bf16* __restrict__ b0, const bf16* __restrict__ b1, const bf16* __restrict__ b2,
    int npass, int K, const float* __restrict__ bias, float* __restrict__ C, int ldc) {
    __shared__ __align__(16) char As[128 * 128];
    __shared__ __align__(16) char Bs[128 * 128];
    const int tid = threadIdx.x;
    const int wid = tid >> 6, lane = tid & 63;
    const int l15 = lane & 15, l4 = lane >> 4;

    const int nbx = gridDim.x, mt = gridDim.y, nwg = nbx * mt;
    const int flat = blockIdx.y * nbx + blockIdx.x;
    const int xcd = flat & 7, o8 = flat >> 3;
    const int q8 = nwg >> 3, r8 = nwg & 7;
    const int wg = (xcd < r8 ? xcd * (q8 + 1) : r8 * (q8 + 1) + (xcd - r8) * q8) + o8;
    const int m0 = (wg % mt) * 128, n0 = (wg / mt) * 128;

    const int wr = (wid >> 1) * 64, wc = (wid & 1) * 64;
    const int swz_rd = (l15 & 7) << 4;
    // pre-swizzled global source for linear LDS dest (m173)
    const int rowL = lane >> 3;                       // 0..7 within chunk
    const int colE = (((lane & 7) ^ rowL)) << 3;      // element offset 0..56

    f32x4 acc[4][4];
#pragma unroll
    for (int i = 0; i < 4; ++i)
#pragma unroll
        for (int j = 0; j < 4; ++j) acc[i][j] = (f32x4){0.f, 0.f, 0.f, 0.f};

    for (int p = 0; p < npass; ++p) {
        const bf16* A = (p == 0) ? a0 : ((p == 1) ? a1 : a2);
        const bf16* B = (p == 0) ? b0 : ((p == 1) ? b1 : b2);
        for (int k0 = 0; k0 < K; k0 += 64) {
            __syncthreads();
#pragma unroll
            for (int c2 = 0; c2 < 4; ++c2) {
                const int ch = wid * 4 + c2;              // 16 chunks of 8 rows
                const int row = ch * 8 + rowL;
                __builtin_amdgcn_global_load_lds(
                    (gas_void*)(A + (size_t)(m0 + row) * K + k0 + colE),
                    (las_void*)(As + ch * 1024), 16, 0, 0);
                __builtin_amdgcn_global_load_lds(
                    (gas_void*)(B + (size_t)(n0 + row) * K + k0 + colE),
                    (las_void*)(Bs + ch * 1024), 16, 0, 0);
            }
            __syncthreads();
#pragma unroll
            for (int ks = 0; ks < 2; ++ks) {
                const int cb = (ks * 64 + l4 * 16) ^ swz_rd;
                bf16x8 af[4], bfr[4];
#pragma unroll
                for (int mi = 0; mi < 4; ++mi)
                    af[mi] = *reinterpret_cast<const bf16x8*>(As + (wr + mi * 16 + l15) * 128 + cb);
#pragma unroll
                for (int ni = 0; ni < 4; ++ni)
                    bfr[ni] = *reinterpret_cast<const bf16x8*>(Bs + (wc + ni * 16 + l15) * 128 + cb);
#pragma unroll
                for (int mi = 0; mi < 4; ++mi)
#pragma unroll
                    for (int ni = 0; ni < 4; ++ni)
                        acc[mi][ni] = MFMA16(af[mi], bfr[ni], acc[mi][ni]);
            }
        }
    }
#pragma unroll
    for (int ni = 0; ni < 4; ++ni) {
        const int col = n0 + wc + ni * 16 + l15;
        const float bv = bias[col];
#pragma unroll
        for (int mi = 0; mi < 4; ++mi) {
            const int row0 = m0 + wr + mi * 16 + l4 * 4;
#pragma unroll
            for (int r = 0; r < 4; ++r)
                C[(size_t)(row0 + r) * ldc + col] = acc[mi][ni][r] + bv;
        }
    }
}

// ---------------------------------------------------------------------------
// Wavefront-persistent LSTM, v3: all staging via global_load_lds (no register
// staging -> no spill). Superstep s computes l0(s), l1(s-1), l2(s-2).
// 256 blocks x 512 thr; block owns 16 gate-cols. 24 chunks/superstep,
// 6 async issues/wave/chunk, double-buffered LDS, distance-1 prefetch with
// raw s_barrier + counted waitcnt. One grid barrier per superstep.
// LDS: buf*49152 + { A-hi [0,16K), A-lo [16K,32K), B [32K,48K) }, pex @98304.
// ---------------------------------------------------------------------------
__global__ __launch_bounds__(512, 1) void lstm_wave(
    const float* __restrict__ c0,
    const bf16* __restrict__ Wh0h, const bf16* __restrict__ Wh0l,
    const bf16* __restrict__ Wi1h, const bf16* __restrict__ Wi1l,
    const bf16* __restrict__ Wh1h, const bf16* __restrict__ Wh1l,
    const bf16* __restrict__ Wi2h, const bf16* __restrict__ Wi2l,
    const bf16* __restrict__ Wh2h, const bf16* __restrict__ Wh2l,
    const float* __restrict__ px0,
    const float* __restrict__ bh0, const float* __restrict__ bi1,
    const float* __restrict__ bh1, const float* __restrict__ bi2,
    const float* __restrict__ bh2,
    bf16* __restrict__ hsb, bf16* __restrict__ outh, int* __restrict__ bar) {
    __shared__ __align__(16) char smem[102400];

    const int tid = threadIdx.x;
    const int lane = tid & 63, wid = tid >> 6;
    const int l15 = lane & 15, l4 = lane >> 4;
    const int wm = wid & 3, wn = wid >> 2;
    const int j0 = blockIdx.x * 4;
    const int lq = l15 >> 2;
    const int lcol = lq * 1024 + j0 + (l15 & 3);
    // async-staging lane geometry (pre-swizzled global source, linear LDS)
    const int lrow = lane >> 4;                  // 0..3 rows within a 1KB seg
    const int lp = lane & 15;                    // 16B piece within row
    const int rA0 = wid * 4 + lrow;              // A seg wid   -> rows
    const int rA1 = (wid + 8) * 4 + lrow;        // A seg wid+8 -> rows
    const size_t offA0 = (size_t)rA0 * HDIM + (size_t)((lp ^ (rA0 & 7)) * 8);
    const size_t offA1 = (size_t)rA1 * HDIM + (size_t)((lp ^ (rA1 & 7)) * 8);
    const int colrW = (wid & 3) * 4 + lrow;      // B col-row for this wave
    const int colgW = (colrW >> 2) * 1024 + j0 + (colrW & 3);
    const size_t offB = (size_t)colgW * HDIM + (size_t)((lp ^ (colrW & 7)) * 8);
    const int hiloW = (wid >> 2) & 1;
    const int ldsA0 = wid * 1024, ldsA1 = (wid + 8) * 1024;
    const int ldsB0 = 32768 + wid * 1024, ldsB1 = 32768 + (wid + 8) * 1024;
    // fragment reads
    const int a_frow = (wm * 16 + l15) * 256;
    const int b_frow = l15 * 256;
    const int swz_r = (l15 & 7) << 4;
    const int kb0 = wn * 128;
    // gates
    const int gb = tid >> 2, gj = tid & 3;

    float biasv0 = 0.f, biasv1 = 0.f, biasv2 = 0.f;
    if (wn == 0) {
        biasv0 = bh0[lcol];
        biasv1 = bi1[lcol] + bh1[lcol];
        biasv2 = bi2[lcol] + bh2[lcol];
    }
    float creg0 = 0.f, creg1 = 0.f, creg2 = 0.f;
    if (tid < 256) {
        creg0 = c0[0 * 65536 + gb * 1024 + j0 + gj];
        creg1 = c0[1 * 65536 + gb * 1024 + j0 + gj];
        creg2 = c0[2 * 65536 + gb * 1024 + j0 + gj];
    }

    auto hsp = [&](int l, int par, int hl) {
        return hsb + (((size_t)l * 2 + par) * 2 + hl) * 65536;
    };

    int barid = 0;
    auto gbar = [&]() {
        __syncthreads();
        if (tid == 0) {
            __hip_atomic_fetch_add(&bar[barid], 1, __ATOMIC_RELEASE,
                                   __HIP_MEMORY_SCOPE_AGENT);
            while (__hip_atomic_load(&bar[barid], __ATOMIC_RELAXED,
                                     __HIP_MEMORY_SCOPE_AGENT) < (int)gridDim.x)
                __builtin_amdgcn_s_sleep(8);
            __builtin_amdgcn_fence(__ATOMIC_ACQUIRE, "agent");
        }
        ++barid;
        __syncthreads();
    };

#define PAH(c)  ((c) < 8 ? A0h : (c) < 16 ? A1h : A2h)
#define PAL(c)  ((c) < 8 ? A0l : (c) < 16 ? A1l : A2l)
#define PB0H(c) ((c) < 8 ? Wh0h : (c) < 16 ? Wh1h : Wh2h)
#define PB0L(c) ((c) < 8 ? Wh0l : (c) < 16 ? Wh1l : Wh2l)
#define PB1H(c) ((c) < 8 ? Wi1h : (c) < 16 ? Wi2h : Wh2h)
#define PB1L(c) ((c) < 8 ? Wi1l : (c) < 16 ? Wi2l : Wh2l)

#define ISSUE(c, buf)                                                            \
    {                                                                            \
        char* base_ = smem + (buf) * 49152;                                      \
        const bf16* pah_ = PAH(c);                                               \
        const bf16* pal_ = PAL(c);                                               \
        const bf16* pb0_ = hiloW ? PB0L(c) : PB0H(c);                            \
        const bf16* pb1_ = hiloW ? PB1L(c) : PB1H(c);                            \
        const size_t ca_ = (size_t)(((c) & 7) * 128);                            \
        __builtin_amdgcn_global_load_lds((gas_void*)(pah_ + offA0 + ca_),        \
                                         (las_void*)(base_ + ldsA0), 16, 0, 0);  \
        __builtin_amdgcn_global_load_lds((gas_void*)(pah_ + offA1 + ca_),        \
                                         (las_void*)(base_ + ldsA1), 16, 0, 0);  \
        __builtin_amdgcn_global_load_lds((gas_void*)(pal_ + offA0 + ca_),        \
                                         (las_void*)(base_ + 16384 + ldsA0), 16, 0, 0); \
        __builtin_amdgcn_global_load_lds((gas_void*)(pal_ + offA1 + ca_),        \
                                         (las_void*)(base_ + 16384 + ldsA1), 16, 0, 0); \
        __builtin_amdgcn_global_load_lds((gas_void*)(pb0_ + offB + ca_),         \
                                         (las_void*)(base_ + ldsB0), 16, 0, 0);  \
        __builtin_amdgcn_global_load_lds((gas_void*)(pb1_ + offB + ca_),         \
                                         (las_void*)(base_ + ldsB1), 16, 0, 0);  \
    }

#define COMPUTE(buf, ACCX, ACCY, TWO, AX, AY)                                    \
    {                                                                            \
        const char* base_ = smem + (buf) * 49152;                                \
        const char* ah_ = base_ + a_frow;                                        \
        const char* al_ = base_ + 16384 + a_frow;                                \
        const char* bb_ = base_ + 32768 + b_frow;                                \
        _Pragma("unroll") for (int ks = 0; ks < 2; ++ks) {                       \
            const int cb = (kb0 + ks * 64 + l4 * 16) ^ swz_r;                    \
            bf16x8 a_h = *reinterpret_cast<const bf16x8*>(ah_ + cb);             \
            bf16x8 a_l = *reinterpret_cast<const bf16x8*>(al_ + cb);             \
            bf16x8 w0h = *reinterpret_cast<const bf16x8*>(bb_ + cb);             \
            bf16x8 w0l = *reinterpret_cast<const bf16x8*>(bb_ + 4096 + cb);      \
            if (AX) {                                                            \
                ACCX = MFMA16(a_h, w0h, ACCX);                                   \
                ACCX = MFMA16(a_h, w0l, ACCX);                                   \
                ACCX = MFMA16(a_l, w0h, ACCX);                                   \
            }                                                                    \
            if (TWO) {                                                           \
                bf16x8 w1h = *reinterpret_cast<const bf16x8*>(bb_ + 8192 + cb);  \
                bf16x8 w1l = *reinterpret_cast<const bf16x8*>(bb_ + 12288 + cb); \
                if (AY) {                                                        \
                    ACCY = MFMA16(a_h, w1h, ACCY);                               \
                    ACCY = MFMA16(a_h, w1l, ACCY);                               \
                    ACCY = MFMA16(a_l, w1h, ACCY);                               \
                }                                                                \
            }                                                                    \
        }                                                                        \
    }

#define WAITBAR()                                                                \
    {                                                                            \
        asm volatile("s_waitcnt vmcnt(0)" ::: "memory");                         \
        __builtin_amdgcn_s_barrier();                                            \
        __builtin_amdgcn_sched_barrier(0);                                       \
    }

#define LBAR()                                                                   \
    {                                                                            \
        asm volatile("s_waitcnt lgkmcnt(0)" ::: "memory");                       \
        __builtin_amdgcn_s_barrier();                                            \
        __builtin_amdgcn_sched_barrier(0);                                       \
    }

#define EPILOGUE(ACC, BIASV, USEPX, ACT, HH, HL, OH, CREG)                       \
    {                                                                            \
        float* pex = reinterpret_cast<float*>(smem + 98304);                     \
        if ((ACT) && wn == 0) {                                                  \
            _Pragma("unroll") for (int r = 0; r < 4; ++r) {                      \
                const int row = wm * 16 + l4 * 4 + r;                            \
                float v = ACC[r] + BIASV;                                        \
                if (USEPX) v += pxv[r];                                          \
                pex[row * 16 + l15] = v;                                         \
            }                                                                    \
        }                                                                        \
        LBAR();                                                                  \
        if ((ACT) && wn == 1) {                                                  \
            _Pragma("unroll") for (int r = 0; r < 4; ++r)                        \
                pex[(wm * 16 + l4 * 4 + r) * 16 + l15] += ACC[r];                \
        }                                                                        \
        LBAR();                                                                  \
        if ((ACT) && tid < 256) {                                                \
            const float pi = pex[gb * 16 + 0 + gj];                              \
            const float pf = pex[gb * 16 + 4 + gj];                              \
            const float po = pex[gb * 16 + 8 + gj];                              \
            const float pg = pex[gb * 16 + 12 + gj];                             \
            const float ig = 1.f / (1.f + expf(-pi));                            \
            const float fg = 1.f / (1.f + expf(-pf));                            \
            const float og = 1.f / (1.f + expf(-po));                            \
            const float gg = tanhf(pg);                                          \
            const float c2v = fg * CREG + ig * gg;                               \
            const float h2v = og * tanhf(c2v);                                   \
            CREG = c2v;                                                          \
            const int idx = gb * 1024 + j0 + gj;                                 \
            const bf16 hhi = (bf16)h2v;                                          \
            HH[idx] = hhi;                                                       \
            HL[idx] = (bf16)(h2v - (float)hhi);                                  \
            if (OH) ((bf16*)(OH))[idx] = hhi;                                    \
        }                                                                        \
    }

#pragma unroll 1
    for (int s = 0; s < T_LEN + 2; ++s) {
        const int ps = s & 1;
        const bool act0 = (s < T_LEN);
        const bool act1 = (s >= 1) && (s <= T_LEN);
        const bool act2 = (s >= 2);

        const bf16* A0h = hsp(0, 1 - ps, 0); const bf16* A0l = hsp(0, 1 - ps, 1);
        const bf16* A1h = hsp(1, ps, 0);     const bf16* A1l = hsp(1, ps, 1);
        const bf16* A2h = hsp(2, 1 - ps, 0); const bf16* A2l = hsp(2, 1 - ps, 1);
        bf16* wH0h = hsp(0, ps, 0);     bf16* wH0l = hsp(0, ps, 1);
        bf16* wH1h = hsp(1, 1 - ps, 0); bf16* wH1l = hsp(1, 1 - ps, 1);
        bf16* wH2h = hsp(2, ps, 0);     bf16* wH2l = hsp(2, ps, 1);
        bf16* ohp = act2 ? (outh + (size_t)(s - 2) * 65536) : nullptr;

        float pxv[4] = {0.f, 0.f, 0.f, 0.f};
        if (wn == 0 && act0) {
            const float* pxr = px0 + (size_t)s * BATCH * GDIM +
                               (size_t)(wm * 16 + l4 * 4) * GDIM + lcol;
#pragma unroll
            for (int r = 0; r < 4; ++r) pxv[r] = pxr[(size_t)r * GDIM];
        }

        f32x4 acc0 = (f32x4){0.f, 0.f, 0.f, 0.f};
        f32x4 acc1 = (f32x4){0.f, 0.f, 0.f, 0.f};
        f32x4 acc2 = (f32x4){0.f, 0.f, 0.f, 0.f};

        ISSUE(0, 0);
        WAITBAR();

#pragma unroll
        for (int i = 0; i < 24; ++i) {
            if (i + 1 < 24) ISSUE(i + 1, (i + 1) & 1)
            if (i < 8)       COMPUTE(i & 1, acc0, acc1, 1, act0, act1)
            else if (i < 16) COMPUTE(i & 1, acc1, acc2, 1, act1, act2)
            else             COMPUTE(i & 1, acc2, acc2, 0, act2, act2)
            WAITBAR();
            if (i == 7)  EPILOGUE(acc0, biasv0, 1, act0, wH0h, wH0l, nullptr, creg0)
            if (i == 15) EPILOGUE(acc1, biasv1, 0, act1, wH1h, wH1l, nullptr, creg1)
            if (i == 23) EPILOGUE(acc2, biasv2, 0, act2, wH2h, wH2l, ohp, creg2)
        }

        if (s < T_LEN + 1) gbar();
    }
#undef PAH
#undef PAL
#undef PB0H
#undef PB0L
#undef PB1H
#undef PB1L
#undef ISSUE
#undef COMPUTE
#undef WAITBAR
#undef LBAR
#undef EPILOGUE
}

// ---------------------------------------------------------------------------
extern "C" void kernel_launch(void* const* d_in, const int* in_sizes, int n_in,
                              void* d_out, int out_size, void* d_ws, size_t ws_size,
                              hipStream_t stream) {
    (void)in_sizes; (void)n_in; (void)out_size; (void)ws_size;
    const int*   x   = (const int*)d_in[0];
    const float* h0  = (const float*)d_in[1];
    const float* c0  = (const float*)d_in[2];
    const float* emb = (const float*)d_in[3];
    const float* W[6] = { (const float*)d_in[4],  (const float*)d_in[6],
                          (const float*)d_in[8],  (const float*)d_in[10],
                          (const float*)d_in[12], (const float*)d_in[14] };
    const float* bi0 = (const float*)d_in[5];
    const float* bh0 = (const float*)d_in[7];
    const float* bi1 = (const float*)d_in[9];
    const float* bh1 = (const float*)d_in[11];
    const float* bi2 = (const float*)d_in[13];
    const float* bh2 = (const float*)d_in[15];
    const float* Wd  = (const float*)d_in[16];
    const float* bd  = (const float*)d_in[17];

    char* ws = (char*)d_ws;
    size_t off = 0;
    float* px0 = (float*)(ws + off); off += (size_t)TBROW * GDIM * 4;
    bf16* wsp[12];
    for (int i = 0; i < 12; ++i) { wsp[i] = (bf16*)(ws + off); off += (size_t)GDIM * HDIM * 2; }
    bf16* wdb  = (bf16*)(ws + off); off += (size_t)VOCAB * HDIM * 2;
    bf16* xeh  = (bf16*)(ws + off); off += (size_t)TBROW * HDIM * 2;
    bf16* xel  = (bf16*)(ws + off); off += (size_t)TBROW * HDIM * 2;
    bf16* outh = (bf16*)(ws + off); off += (size_t)TBROW * HDIM * 2;
    bf16* hsb  = (bf16*)(ws + off); off += (size_t)12 * BATCH * HDIM * 2;
    float* cst = (float*)(ws + off); off += (size_t)3 * BATCH * HDIM * 4;
    int*  bar  = (int*)(ws + off);  off += 1024;

    // wsp[0..1]=Wi0, [2..3]=Wh0, [4..5]=Wi1, [6..7]=Wh1, [8..9]=Wi2, [10..11]=Wh2
    for (int i = 0; i < 6; ++i)
        split_kernel<<<1024, 256, 0, stream>>>(W[i], wsp[2 * i], wsp[2 * i + 1],
                                               GDIM * HDIM / 4);
    conv_kernel<<<2048, 256, 0, stream>>>(Wd, wdb, VOCAB * HDIM / 4);
    embed_kernel<<<TBROW, 256, 0, stream>>>(x, emb, xeh, xel);
    init_kernel<<<768, 256, 0, stream>>>(h0, c0, hsb, cst);
    hipMemsetAsync(bar, 0, 1024, stream);

    // px0 = xe @ Wi0^T + bi0 (split-3)
    dim3 gpx(GDIM / 128, TBROW / 128);
    gemm_bt<<<gpx, 256, 0, stream>>>(xeh, xel, xeh, wsp[0], wsp[0], wsp[1],
                                     3, HDIM, bi0, px0, GDIM);

    // whole recurrence: wavefront-persistent, async-staged
    lstm_wave<<<256, 512, 0, stream>>>(
        c0,
        wsp[2], wsp[3],           // Wh0
        wsp[4], wsp[5],           // Wi1
        wsp[6], wsp[7],           // Wh1
        wsp[8], wsp[9],           // Wi2
        wsp[10], wsp[11],         // Wh2
        px0, bh0, bi1, bh1, bi2, bh2,
        hsb, outh, bar);

    // decoder: d_out = outh @ Wd^T + bd
    dim3 gdec(VOCAB / 128, TBROW / 128);
    gemm_bt<<<gdec, 256, 0, stream>>>(outh, nullptr, nullptr, wdb, nullptr, nullptr,
                                      1, HDIM, bd, (float*)d_out, VOCAB);
}

// Round 7
// 2835.994 us; speedup vs baseline: 2.7274x; 1.0706x over previous
//
#include <hip/hip_runtime.h>

typedef __bf16 bf16;
typedef __bf16 bf16x8 __attribute__((ext_vector_type(8)));
typedef __bf16 bf16x4 __attribute__((ext_vector_type(4)));
typedef float  f32x4  __attribute__((ext_vector_type(4)));

#define T_LEN 70
#define BATCH 64
#define HDIM  1024
#define GDIM  4096
#define VOCAB 32000
#define TBROW (T_LEN * BATCH)   // 4480

#define MFMA16(a, b, c) __builtin_amdgcn_mfma_f32_16x16x32_bf16((a), (b), (c), 0, 0, 0)

typedef const __attribute__((address_space(1))) void gas_void;
typedef __attribute__((address_space(3))) void las_void;

// ---------------------------------------------------------------------------
// fp32 -> bf16 hi/lo split
// ---------------------------------------------------------------------------
__global__ void split_kernel(const float* __restrict__ w, bf16* __restrict__ hi,
                             bf16* __restrict__ lo, int n4) {
    int stride = gridDim.x * blockDim.x;
    for (int i = blockIdx.x * blockDim.x + threadIdx.x; i < n4; i += stride) {
        float4 v = reinterpret_cast<const float4*>(w)[i];
        bf16 h0 = (bf16)v.x, h1 = (bf16)v.y, h2 = (bf16)v.z, h3 = (bf16)v.w;
        bf16x4 hv = {h0, h1, h2, h3};
        bf16x4 lv = {(bf16)(v.x - (float)h0), (bf16)(v.y - (float)h1),
                     (bf16)(v.z - (float)h2), (bf16)(v.w - (float)h3)};
        reinterpret_cast<bf16x4*>(hi)[i] = hv;
        reinterpret_cast<bf16x4*>(lo)[i] = lv;
    }
}

__global__ void conv_kernel(const float* __restrict__ w, bf16* __restrict__ hi, int n4) {
    int stride = gridDim.x * blockDim.x;
    for (int i = blockIdx.x * blockDim.x + threadIdx.x; i < n4; i += stride) {
        float4 v = reinterpret_cast<const float4*>(w)[i];
        bf16x4 hv = {(bf16)v.x, (bf16)v.y, (bf16)v.z, (bf16)v.w};
        reinterpret_cast<bf16x4*>(hi)[i] = hv;
    }
}

__global__ void embed_kernel(const int* __restrict__ x, const float* __restrict__ emb,
                             bf16* __restrict__ xh, bf16* __restrict__ xl) {
    int row = blockIdx.x;
    int tok = x[row];
    const float4* src = reinterpret_cast<const float4*>(emb + (size_t)tok * HDIM);
    bf16x4* dh = reinterpret_cast<bf16x4*>(xh + (size_t)row * HDIM);
    bf16x4* dl = reinterpret_cast<bf16x4*>(xl + (size_t)row * HDIM);
    for (int i = threadIdx.x; i < HDIM / 4; i += blockDim.x) {
        float4 v = src[i];
        bf16 h0 = (bf16)v.x, h1 = (bf16)v.y, h2 = (bf16)v.z, h3 = (bf16)v.w;
        dh[i] = (bf16x4){h0, h1, h2, h3};
        dl[i] = (bf16x4){(bf16)(v.x - (float)h0), (bf16)(v.y - (float)h1),
                         (bf16)(v.z - (float)h2), (bf16)(v.w - (float)h3)};
    }
}

// initial h stored at parity 1 (first reads occur at input-parity 1)
__global__ void init_kernel(const float* __restrict__ h0, const float* __restrict__ c0,
                            bf16* __restrict__ hsb, float* __restrict__ cst) {
    int i = blockIdx.x * blockDim.x + threadIdx.x;
    int l = i >> 16, r = i & 65535;
    float v = h0[i];
    bf16 h = (bf16)v;
    hsb[(size_t)((l * 2 + 1) * 2 + 0) * 65536 + r] = h;
    hsb[(size_t)((l * 2 + 1) * 2 + 1) * 65536 + r] = (bf16)(v - (float)h);
    cst[i] = c0[i];
}

// ---------------------------------------------------------------------------
// GEMM C = sum_p A_p B_p^T + bias. 128x128 tile, global_load_lds width-16
// staging with pre-swizzled global source (linear LDS dest), XOR-swizzled
// fragment reads. XCD-bijective remap, m-fastest within XCD.
// ---------------------------------------------------------------------------
__global__ __launch_bounds__(256) void gemm_bt(
    const bf16* __restrict__ a0, const bf16* __restrict__ a1, const bf16* __restrict__ a2,
    const bf16* __restrict__ b0, const bf16* __restrict__ b1, const bf16* __restrict__ b2,
    int npass, int K, const float* __restrict__ bias, float* __restrict__ C, int ldc) {
    __shared__ __align__(16) char As[128 * 128];
    __shared__ __align__(16) char Bs[128 * 128];
    const int tid = threadIdx.x;
    const int wid = tid >> 6, lane = tid & 63;
    const int l15 = lane & 15, l4 = lane >> 4;

    const int nbx = gridDim.x, mt = gridDim.y, nwg = nbx * mt;
    const int flat = blockIdx.y * nbx + blockIdx.x;
    const int xcd = flat & 7, o8 = flat >> 3;
    const int q8 = nwg >> 3, r8 = nwg & 7;
    const int wg = (xcd < r8 ? xcd * (q8 + 1) : r8 * (q8 + 1) + (xcd - r8) * q8) + o8;
    const int m0 = (wg % mt) * 128, n0 = (wg / mt) * 128;

    const int wr = (wid >> 1) * 64, wc = (wid & 1) * 64;
    const int swz_rd = (l15 & 7) << 4;
    // pre-swizzled global source for linear LDS dest (m173)
    const int rowL = lane >> 3;                       // 0..7 within chunk
    const int colE = (((lane & 7) ^ rowL)) << 3;      // element offset 0..56

    f32x4 acc[4][4];
#pragma unroll
    for (int i = 0; i < 4; ++i)
#pragma unroll
        for (int j = 0; j < 4; ++j) acc[i][j] = (f32x4){0.f, 0.f, 0.f, 0.f};

    for (int p = 0; p < npass; ++p) {
        const bf16* A = (p == 0) ? a0 : ((p == 1) ? a1 : a2);
        const bf16* B = (p == 0) ? b0 : ((p == 1) ? b1 : b2);
        for (int k0 = 0; k0 < K; k0 += 64) {
            __syncthreads();
#pragma unroll
            for (int c2 = 0; c2 < 4; ++c2) {
                const int ch = wid * 4 + c2;              // 16 chunks of 8 rows
                const int row = ch * 8 + rowL;
                __builtin_amdgcn_global_load_lds(
                    (gas_void*)(A + (size_t)(m0 + row) * K + k0 + colE),
                    (las_void*)(As + ch * 1024), 16, 0, 0);
                __builtin_amdgcn_global_load_lds(
                    (gas_void*)(B + (size_t)(n0 + row) * K + k0 + colE),
                    (las_void*)(Bs + ch * 1024), 16, 0, 0);
            }
            __syncthreads();
#pragma unroll
            for (int ks = 0; ks < 2; ++ks) {
                const int cb = (ks * 64 + l4 * 16) ^ swz_rd;
                bf16x8 af[4], bfr[4];
#pragma unroll
                for (int mi = 0; mi < 4; ++mi)
                    af[mi] = *reinterpret_cast<const bf16x8*>(As + (wr + mi * 16 + l15) * 128 + cb);
#pragma unroll
                for (int ni = 0; ni < 4; ++ni)
                    bfr[ni] = *reinterpret_cast<const bf16x8*>(Bs + (wc + ni * 16 + l15) * 128 + cb);
#pragma unroll
                for (int mi = 0; mi < 4; ++mi)
#pragma unroll
                    for (int ni = 0; ni < 4; ++ni)
                        acc[mi][ni] = MFMA16(af[mi], bfr[ni], acc[mi][ni]);
            }
        }
    }
#pragma unroll
    for (int ni = 0; ni < 4; ++ni) {
        const int col = n0 + wc + ni * 16 + l15;
        const float bv = bias[col];
#pragma unroll
        for (int mi = 0; mi < 4; ++mi) {
            const int row0 = m0 + wr + mi * 16 + l4 * 4;
#pragma unroll
            for (int r = 0; r < 4; ++r)
                C[(size_t)(row0 + r) * ldc + col] = acc[mi][ni][r] + bv;
        }
    }
}

// ---------------------------------------------------------------------------
// Wavefront-persistent LSTM, v4: triple-buffered LDS, distance-2 prefetch,
// COUNTED vmcnt (never drained mid-loop), explicit unrolled 24-chunk schedule,
// second barrier per chunk (compute-done) so ISSUE never races readers.
// Group-2 duplicate Wh2 staging removed (5 loads/chunk for c>=16).
// Full 4-bit XOR swizzle (row&15) on stage-source and reads.
// ---------------------------------------------------------------------------
__global__ __launch_bounds__(512, 1) void lstm_wave(
    const float* __restrict__ c0,
    const bf16* __restrict__ Wh0h, const bf16* __restrict__ Wh0l,
    const bf16* __restrict__ Wi1h, const bf16* __restrict__ Wi1l,
    const bf16* __restrict__ Wh1h, const bf16* __restrict__ Wh1l,
    const bf16* __restrict__ Wi2h, const bf16* __restrict__ Wi2l,
    const bf16* __restrict__ Wh2h, const bf16* __restrict__ Wh2l,
    const float* __restrict__ px0,
    const float* __restrict__ bh0, const float* __restrict__ bi1,
    const float* __restrict__ bh1, const float* __restrict__ bi2,
    const float* __restrict__ bh2,
    bf16* __restrict__ hsb, bf16* __restrict__ outh, int* __restrict__ bar) {
    // buf*49152 + { A-hi [0,16K), A-lo [16K,32K), B [32K,48K) }, 3 bufs.
    // pex float[64][16] at 147456.
    __shared__ __align__(16) char smem[151552];

    const int tid = threadIdx.x;
    const int lane = tid & 63, wid = tid >> 6;
    const int l15 = lane & 15, l4 = lane >> 4;
    const int wm = wid & 3, wn = wid >> 2;
    const int j0 = blockIdx.x * 4;
    const int lq = l15 >> 2;
    const int lcol = lq * 1024 + j0 + (l15 & 3);
    // async-staging lane geometry (pre-swizzled global source, linear LDS)
    const int lrow = lane >> 4;                  // 0..3 rows within a 1KB seg
    const int lp = lane & 15;                    // 16B piece within row
    const int rA0 = wid * 4 + lrow;              // A seg wid   -> rows 0..31
    const int rA1 = (wid + 8) * 4 + lrow;        // A seg wid+8 -> rows 32..63
    const size_t offA0 = (size_t)rA0 * HDIM + (size_t)((lp ^ (rA0 & 15)) * 8);
    const size_t offA1 = (size_t)rA1 * HDIM + (size_t)((lp ^ (rA1 & 15)) * 8);
    const int colrW = (wid & 3) * 4 + lrow;      // B col-row 0..15
    const int colgW = (colrW >> 2) * 1024 + j0 + (colrW & 3);
    const size_t offB = (size_t)colgW * HDIM + (size_t)((lp ^ (colrW & 15)) * 8);
    const int hiloW = (wid >> 2) & 1;
    const int ldsA0 = wid * 1024, ldsA1 = (wid + 8) * 1024;
    const int ldsB0 = 32768 + wid * 1024, ldsB1 = 32768 + (wid + 8) * 1024;
    // fragment reads (4-bit XOR)
    const int a_frow = (wm * 16 + l15) * 256;
    const int b_frow = l15 * 256;
    const int swz_r = l15 << 4;
    const int kb0 = wn * 128;
    // gates
    const int gb = tid >> 2, gj = tid & 3;

    float biasv0 = 0.f, biasv1 = 0.f, biasv2 = 0.f;
    if (wn == 0) {
        biasv0 = bh0[lcol];
        biasv1 = bi1[lcol] + bh1[lcol];
        biasv2 = bi2[lcol] + bh2[lcol];
    }
    float creg0 = 0.f, creg1 = 0.f, creg2 = 0.f;
    if (tid < 256) {
        creg0 = c0[0 * 65536 + gb * 1024 + j0 + gj];
        creg1 = c0[1 * 65536 + gb * 1024 + j0 + gj];
        creg2 = c0[2 * 65536 + gb * 1024 + j0 + gj];
    }

    auto hsp = [&](int l, int par, int hl) {
        return hsb + (((size_t)l * 2 + par) * 2 + hl) * 65536;
    };

    int barid = 0;
    auto gbar = [&]() {
        __syncthreads();
        if (tid == 0) {
            __hip_atomic_fetch_add(&bar[barid], 1, __ATOMIC_RELEASE,
                                   __HIP_MEMORY_SCOPE_AGENT);
            while (__hip_atomic_load(&bar[barid], __ATOMIC_RELAXED,
                                     __HIP_MEMORY_SCOPE_AGENT) < (int)gridDim.x)
                __builtin_amdgcn_s_sleep(8);
            __builtin_amdgcn_fence(__ATOMIC_ACQUIRE, "agent");
        }
        ++barid;
        __syncthreads();
    };

#define PAH(c)  ((c) < 8 ? A0h : (c) < 16 ? A1h : A2h)
#define PAL(c)  ((c) < 8 ? A0l : (c) < 16 ? A1l : A2l)
#define PB0H(c) ((c) < 8 ? Wh0h : (c) < 16 ? Wh1h : Wh2h)
#define PB0L(c) ((c) < 8 ? Wh0l : (c) < 16 ? Wh1l : Wh2l)
#define PB1H(c) ((c) < 8 ? Wi1h : Wi2h)
#define PB1L(c) ((c) < 8 ? Wi1l : Wi2l)

// 6 loads/chunk when TWOB, else 5
#define ISSUE(c, buf, TWOB)                                                      \
    {                                                                            \
        char* base_ = smem + (buf) * 49152;                                      \
        const bf16* pah_ = PAH(c);                                               \
        const bf16* pal_ = PAL(c);                                               \
        const bf16* pb0_ = hiloW ? PB0L(c) : PB0H(c);                            \
        const size_t ca_ = (size_t)(((c) & 7) * 128);                            \
        __builtin_amdgcn_global_load_lds((gas_void*)(pah_ + offA0 + ca_),        \
                                         (las_void*)(base_ + ldsA0), 16, 0, 0);  \
        __builtin_amdgcn_global_load_lds((gas_void*)(pah_ + offA1 + ca_),        \
                                         (las_void*)(base_ + ldsA1), 16, 0, 0);  \
        __builtin_amdgcn_global_load_lds((gas_void*)(pal_ + offA0 + ca_),        \
                                         (las_void*)(base_ + 16384 + ldsA0), 16, 0, 0); \
        __builtin_amdgcn_global_load_lds((gas_void*)(pal_ + offA1 + ca_),        \
                                         (las_void*)(base_ + 16384 + ldsA1), 16, 0, 0); \
        __builtin_amdgcn_global_load_lds((gas_void*)(pb0_ + offB + ca_),         \
                                         (las_void*)(base_ + ldsB0), 16, 0, 0);  \
        if (TWOB) {                                                              \
            const bf16* pb1_ = hiloW ? PB1L(c) : PB1H(c);                        \
            __builtin_amdgcn_global_load_lds((gas_void*)(pb1_ + offB + ca_),     \
                                             (las_void*)(base_ + ldsB1), 16, 0, 0); \
        }                                                                        \
    }

#define COMPUTE(buf, ACCX, ACCY, TWO, AX, AY)                                    \
    {                                                                            \
        const char* base_ = smem + (buf) * 49152;                                \
        const char* ah_ = base_ + a_frow;                                        \
        const char* al_ = base_ + 16384 + a_frow;                                \
        const char* bb_ = base_ + 32768 + b_frow;                                \
        _Pragma("unroll") for (int ks = 0; ks < 2; ++ks) {                       \
            const int cb = (kb0 + ks * 64 + l4 * 16) ^ swz_r;                    \
            bf16x8 a_h = *reinterpret_cast<const bf16x8*>(ah_ + cb);             \
            bf16x8 a_l = *reinterpret_cast<const bf16x8*>(al_ + cb);             \
            bf16x8 w0h = *reinterpret_cast<const bf16x8*>(bb_ + cb);             \
            bf16x8 w0l = *reinterpret_cast<const bf16x8*>(bb_ + 4096 + cb);      \
            if (AX) {                                                            \
                ACCX = MFMA16(a_h, w0h, ACCX);                                   \
                ACCX = MFMA16(a_h, w0l, ACCX);                                   \
                ACCX = MFMA16(a_l, w0h, ACCX);                                   \
            }                                                                    \
            if (TWO) {                                                           \
                bf16x8 w1h = *reinterpret_cast<const bf16x8*>(bb_ + 8192 + cb);  \
                bf16x8 w1l = *reinterpret_cast<const bf16x8*>(bb_ + 12288 + cb); \
                if (AY) {                                                        \
                    ACCY = MFMA16(a_h, w1h, ACCY);                               \
                    ACCY = MFMA16(a_h, w1l, ACCY);                               \
                    ACCY = MFMA16(a_l, w1h, ACCY);                               \
                }                                                                \
            }                                                                    \
        }                                                                        \
    }

// counted-vmcnt wait + data-ready barrier (N = loads still allowed in flight)
#define WAITBAR(N)                                                               \
    {                                                                            \
        asm volatile("s_waitcnt vmcnt(" #N ")" ::: "memory");                    \
        __builtin_amdgcn_s_barrier();                                            \
        __builtin_amdgcn_sched_barrier(0);                                       \
    }

// compute-done barrier (before overwriting the buffer just read)
#define BAR2()                                                                   \
    {                                                                            \
        __builtin_amdgcn_s_barrier();                                            \
        __builtin_amdgcn_sched_barrier(0);                                       \
    }

#define LBAR()                                                                   \
    {                                                                            \
        asm volatile("s_waitcnt lgkmcnt(0)" ::: "memory");                       \
        __builtin_amdgcn_s_barrier();                                            \
        __builtin_amdgcn_sched_barrier(0);                                       \
    }

#define EPILOGUE(ACC, BIASV, USEPX, ACT, HH, HL, OH, CREG)                       \
    {                                                                            \
        float* pex = reinterpret_cast<float*>(smem + 147456);                    \
        if ((ACT) && wn == 0) {                                                  \
            _Pragma("unroll") for (int r = 0; r < 4; ++r) {                      \
                const int row = wm * 16 + l4 * 4 + r;                            \
                float v = ACC[r] + BIASV;                                        \
                if (USEPX) v += pxv[r];                                          \
                pex[row * 16 + l15] = v;                                         \
            }                                                                    \
        }                                                                        \
        LBAR();                                                                  \
        if ((ACT) && wn == 1) {                                                  \
            _Pragma("unroll") for (int r = 0; r < 4; ++r)                        \
                pex[(wm * 16 + l4 * 4 + r) * 16 + l15] += ACC[r];                \
        }                                                                        \
        LBAR();                                                                  \
        if ((ACT) && tid < 256) {                                                \
            const float pi = pex[gb * 16 + 0 + gj];                              \
            const float pf = pex[gb * 16 + 4 + gj];                              \
            const float po = pex[gb * 16 + 8 + gj];                              \
            const float pg = pex[gb * 16 + 12 + gj];                             \
            const float ig = 1.f / (1.f + expf(-pi));                            \
            const float fg = 1.f / (1.f + expf(-pf));                            \
            const float og = 1.f / (1.f + expf(-po));                            \
            const float gg = tanhf(pg);                                          \
            const float c2v = fg * CREG + ig * gg;                               \
            const float h2v = og * tanhf(c2v);                                   \
            CREG = c2v;                                                          \
            const int idx = gb * 1024 + j0 + gj;                                 \
            const bf16 hhi = (bf16)h2v;                                          \
            HH[idx] = hhi;                                                       \
            HL[idx] = (bf16)(h2v - (float)hhi);                                  \
            if (OH) ((bf16*)(OH))[idx] = hhi;                                    \
        }                                                                        \
    }

#pragma unroll 1
    for (int s = 0; s < T_LEN + 2; ++s) {
        const int ps = s & 1;
        const bool act0 = (s < T_LEN);
        const bool act1 = (s >= 1) && (s <= T_LEN);
        const bool act2 = (s >= 2);

        const bf16* A0h = hsp(0, 1 - ps, 0); const bf16* A0l = hsp(0, 1 - ps, 1);
        const bf16* A1h = hsp(1, ps, 0);     const bf16* A1l = hsp(1, ps, 1);
        const bf16* A2h = hsp(2, 1 - ps, 0); const bf16* A2l = hsp(2, 1 - ps, 1);
        bf16* wH0h = hsp(0, ps, 0);     bf16* wH0l = hsp(0, ps, 1);
        bf16* wH1h = hsp(1, 1 - ps, 0); bf16* wH1l = hsp(1, 1 - ps, 1);
        bf16* wH2h = hsp(2, ps, 0);     bf16* wH2l = hsp(2, ps, 1);
        bf16* ohp = act2 ? (outh + (size_t)(s - 2) * 65536) : nullptr;

        float pxv[4] = {0.f, 0.f, 0.f, 0.f};
        if (wn == 0 && act0) {
            const float* pxr = px0 + (size_t)s * BATCH * GDIM +
                               (size_t)(wm * 16 + l4 * 4) * GDIM + lcol;
#pragma unroll
            for (int r = 0; r < 4; ++r) pxv[r] = pxr[(size_t)r * GDIM];
        }

        f32x4 acc0 = (f32x4){0.f, 0.f, 0.f, 0.f};
        f32x4 acc1 = (f32x4){0.f, 0.f, 0.f, 0.f};
        f32x4 acc2 = (f32x4){0.f, 0.f, 0.f, 0.f};

        // prologue: 3 chunks in flight
        ISSUE(0, 0, 1) ISSUE(1, 1, 1) ISSUE(2, 2, 1)

        // ---- group 0: chunks 0-7 (acc0 += A0@Wh0 ; acc1 += A0@Wi1) ----
        WAITBAR(12) COMPUTE(0, acc0, acc1, 1, act0, act1) BAR2() ISSUE(3, 0, 1)
        WAITBAR(12) COMPUTE(1, acc0, acc1, 1, act0, act1) BAR2() ISSUE(4, 1, 1)
        WAITBAR(12) COMPUTE(2, acc0, acc1, 1, act0, act1) BAR2() ISSUE(5, 2, 1)
        WAITBAR(12) COMPUTE(0, acc0, acc1, 1, act0, act1) BAR2() ISSUE(6, 0, 1)
        WAITBAR(12) COMPUTE(1, acc0, acc1, 1, act0, act1) BAR2() ISSUE(7, 1, 1)
        WAITBAR(12) COMPUTE(2, acc0, acc1, 1, act0, act1) BAR2() ISSUE(8, 2, 1)
        WAITBAR(12) COMPUTE(0, acc0, acc1, 1, act0, act1) BAR2() ISSUE(9, 0, 1)
        WAITBAR(12) COMPUTE(1, acc0, acc1, 1, act0, act1) BAR2() ISSUE(10, 1, 1)
        EPILOGUE(acc0, biasv0, 1, act0, wH0h, wH0l, nullptr, creg0)

        // ---- group 1: chunks 8-15 (acc1 += A1@Wh1 ; acc2 += A1@Wi2) ----
        WAITBAR(12) COMPUTE(2, acc1, acc2, 1, act1, act2) BAR2() ISSUE(11, 2, 1)
        WAITBAR(12) COMPUTE(0, acc1, acc2, 1, act1, act2) BAR2() ISSUE(12, 0, 1)
        WAITBAR(12) COMPUTE(1, acc1, acc2, 1, act1, act2) BAR2() ISSUE(13, 1, 1)
        WAITBAR(12) COMPUTE(2, acc1, acc2, 1, act1, act2) BAR2() ISSUE(14, 2, 1)
        WAITBAR(12) COMPUTE(0, acc1, acc2, 1, act1, act2) BAR2() ISSUE(15, 0, 1)
        WAITBAR(12) COMPUTE(1, acc1, acc2, 1, act1, act2) BAR2() ISSUE(16, 1, 0)
        WAITBAR(11) COMPUTE(2, acc1, acc2, 1, act1, act2) BAR2() ISSUE(17, 2, 0)
        WAITBAR(10) COMPUTE(0, acc1, acc2, 1, act1, act2) BAR2() ISSUE(18, 0, 0)
        EPILOGUE(acc1, biasv1, 0, act1, wH1h, wH1l, nullptr, creg1)

        // ---- group 2: chunks 16-23 (acc2 += A2@Wh2) ----
        WAITBAR(10) COMPUTE(1, acc2, acc2, 0, act2, act2) BAR2() ISSUE(19, 1, 0)
        WAITBAR(10) COMPUTE(2, acc2, acc2, 0, act2, act2) BAR2() ISSUE(20, 2, 0)
        WAITBAR(10) COMPUTE(0, acc2, acc2, 0, act2, act2) BAR2() ISSUE(21, 0, 0)
        WAITBAR(10) COMPUTE(1, acc2, acc2, 0, act2, act2) BAR2() ISSUE(22, 1, 0)
        WAITBAR(10) COMPUTE(2, acc2, acc2, 0, act2, act2) BAR2() ISSUE(23, 2, 0)
        WAITBAR(10) COMPUTE(0, acc2, acc2, 0, act2, act2) BAR2()
        WAITBAR(5)  COMPUTE(1, acc2, acc2, 0, act2, act2) BAR2()
        WAITBAR(0)  COMPUTE(2, acc2, acc2, 0, act2, act2) BAR2()
        EPILOGUE(acc2, biasv2, 0, act2, wH2h, wH2l, ohp, creg2)

        if (s < T_LEN + 1) gbar();
    }
#undef PAH
#undef PAL
#undef PB0H
#undef PB0L
#undef PB1H
#undef PB1L
#undef ISSUE
#undef COMPUTE
#undef WAITBAR
#undef BAR2
#undef LBAR
#undef EPILOGUE
}

// ---------------------------------------------------------------------------
extern "C" void kernel_launch(void* const* d_in, const int* in_sizes, int n_in,
                              void* d_out, int out_size, void* d_ws, size_t ws_size,
                              hipStream_t stream) {
    (void)in_sizes; (void)n_in; (void)out_size; (void)ws_size;
    const int*   x   = (const int*)d_in[0];
    const float* h0  = (const float*)d_in[1];
    const float* c0  = (const float*)d_in[2];
    const float* emb = (const float*)d_in[3];
    const float* W[6] = { (const float*)d_in[4],  (const float*)d_in[6],
                          (const float*)d_in[8],  (const float*)d_in[10],
                          (const float*)d_in[12], (const float*)d_in[14] };
    const float* bi0 = (const float*)d_in[5];
    const float* bh0 = (const float*)d_in[7];
    const float* bi1 = (const float*)d_in[9];
    const float* bh1 = (const float*)d_in[11];
    const float* bi2 = (const float*)d_in[13];
    const float* bh2 = (const float*)d_in[15];
    const float* Wd  = (const float*)d_in[16];
    const float* bd  = (const float*)d_in[17];

    char* ws = (char*)d_ws;
    size_t off = 0;
    float* px0 = (float*)(ws + off); off += (size_t)TBROW * GDIM * 4;
    bf16* wsp[12];
    for (int i = 0; i < 12; ++i) { wsp[i] = (bf16*)(ws + off); off += (size_t)GDIM * HDIM * 2; }
    bf16* wdb  = (bf16*)(ws + off); off += (size_t)VOCAB * HDIM * 2;
    bf16* xeh  = (bf16*)(ws + off); off += (size_t)TBROW * HDIM * 2;
    bf16* xel  = (bf16*)(ws + off); off += (size_t)TBROW * HDIM * 2;
    bf16* outh = (bf16*)(ws + off); off += (size_t)TBROW * HDIM * 2;
    bf16* hsb  = (bf16*)(ws + off); off += (size_t)12 * BATCH * HDIM * 2;
    float* cst = (float*)(ws + off); off += (size_t)3 * BATCH * HDIM * 4;
    int*  bar  = (int*)(ws + off);  off += 1024;

    // wsp[0..1]=Wi0, [2..3]=Wh0, [4..5]=Wi1, [6..7]=Wh1, [8..9]=Wi2, [10..11]=Wh2
    for (int i = 0; i < 6; ++i)
        split_kernel<<<1024, 256, 0, stream>>>(W[i], wsp[2 * i], wsp[2 * i + 1],
                                               GDIM * HDIM / 4);
    conv_kernel<<<2048, 256, 0, stream>>>(Wd, wdb, VOCAB * HDIM / 4);
    embed_kernel<<<TBROW, 256, 0, stream>>>(x, emb, xeh, xel);
    init_kernel<<<768, 256, 0, stream>>>(h0, c0, hsb, cst);
    hipMemsetAsync(bar, 0, 1024, stream);

    // px0 = xe @ Wi0^T + bi0 (split-3)
    dim3 gpx(GDIM / 128, TBROW / 128);
    gemm_bt<<<gpx, 256, 0, stream>>>(xeh, xel, xeh, wsp[0], wsp[0], wsp[1],
                                     3, HDIM, bi0, px0, GDIM);

    // whole recurrence: wavefront-persistent, deep-pipelined async staging
    lstm_wave<<<256, 512, 0, stream>>>(
        c0,
        wsp[2], wsp[3],           // Wh0
        wsp[4], wsp[5],           // Wi1
        wsp[6], wsp[7],           // Wh1
        wsp[8], wsp[9],           // Wi2
        wsp[10], wsp[11],         // Wh2
        px0, bh0, bi1, bh1, bi2, bh2,
        hsb, outh, bar);

    // decoder: d_out = outh @ Wd^T + bd
    dim3 gdec(VOCAB / 128, TBROW / 128);
    gemm_bt<<<gdec, 256, 0, stream>>>(outh, nullptr, nullptr, wdb, nullptr, nullptr,
                                      1, HDIM, bd, (float*)d_out, VOCAB);
}